// Round 10
// baseline (317.400 us; speedup 1.0000x reference)
//
#include <hip/hip_runtime.h>
#include <hip/hip_bf16.h>

#define NDT 30000
#define NOD 10000
#define NE1 500000
#define NE2 300000
#define NEL 200000
#define CAP_DT 64
#define CAP_OD 96
#define NCHUNK 60

typedef unsigned short ushort_t;
typedef unsigned int uint_t;
typedef __attribute__((ext_vector_type(8))) short short8;
typedef __attribute__((ext_vector_type(4))) float f32x4;

// ---------------- workspace layout ----------------
// float region
static constexpr size_t F_BFUSE = 0;                          // 64
static constexpr size_t F_ENDF  = 64;
// ushort region (base = (ushort_t*)(W + F_ENDF))
static constexpr size_t U_XDT    = 0;                          // 30000*128
static constexpr size_t U_XOD    = U_XDT + (size_t)NDT * 128;  // 10000*64
static constexpr size_t U_AGGX   = U_XOD + (size_t)NOD * 64;   // 30000*128 (agg_x, later agg_d)
static constexpr size_t U_H      = U_AGGX + (size_t)NDT * 128; // h, later d2
static constexpr size_t U_D1     = U_H + (size_t)NDT * 128;
static constexpr size_t U_AGGH   = U_D1 + (size_t)NDT * 128;   // 10000*128
static constexpr size_t U_OD2    = U_AGGH + (size_t)NOD * 128;
static constexpr size_t U_OD3    = U_OD2 + (size_t)NOD * 128;
static constexpr size_t U_WT1A   = U_OD3 + (size_t)NOD * 128;  // 128*256
static constexpr size_t U_WT1B   = U_WT1A + 32768;
static constexpr size_t U_WTOD2  = U_WT1B + 32768;             // 128*192
static constexpr size_t U_WTOD3  = U_WTOD2 + 24576;
static constexpr size_t U_WTDT2  = U_WTOD3 + 32768;
static constexpr size_t U_WLODT  = U_WTDT2 + 32768;            // 64*128
static constexpr size_t U_WLDTT  = U_WLODT + 8192;
static constexpr size_t U_POD    = U_WLDTT + 8192;             // 10000*64 bf16
static constexpr size_t U_PDT    = U_POD + (size_t)NOD * 64;   // 30000*64 bf16
static constexpr size_t U_SRC_DT = U_PDT + (size_t)NDT * 64;   // 30000*64 ushort
static constexpr size_t U_SRC_OD = U_SRC_DT + (size_t)NDT * CAP_DT; // 10000*96 ushort
static constexpr size_t U_END    = U_SRC_OD + (size_t)NOD * CAP_OD;
// int region (base = int* after U; memset covers both cnt arrays)
static constexpr size_t I_CNT_DT = 0;        // 30000
static constexpr size_t I_CNT_OD = 30000;    // 10000

__device__ __forceinline__ ushort_t f2bf(float f) {
    uint_t u = __float_as_uint(f);
    return (ushort_t)((u + 0x7fffu + ((u >> 16) & 1u)) >> 16);
}
__device__ __forceinline__ float bf2f(uint_t lo16) { return __uint_as_float(lo16 << 16); }

// ---------------- conversions: x tables -> bf16 ----------------
__global__ __launch_bounds__(256) void conv_bf(const float* __restrict__ x_dt, const float* __restrict__ x_od,
                                               ushort_t* __restrict__ xdt_bf, ushort_t* __restrict__ xod_bf) {
    int i = blockIdx.x * 256 + threadIdx.x;
    size_t i4 = (size_t)i * 4;
    const size_t n_dt = (size_t)NDT * 128, n_od = (size_t)NOD * 64;
    if (i4 < n_dt) {
        float4 v = *(const float4*)(x_dt + i4);
        ushort4 o = { f2bf(v.x), f2bf(v.y), f2bf(v.z), f2bf(v.w) };
        *(ushort4*)(xdt_bf + i4) = o;
    } else if (i4 - n_dt < n_od) {
        size_t j = i4 - n_dt;
        float4 v = *(const float4*)(x_od + j);
        ushort4 o = { f2bf(v.x), f2bf(v.y), f2bf(v.z), f2bf(v.w) };
        *(ushort4*)(xod_bf + j) = o;
    }
}

// ---------------- prep: combined transposed bf16 weights Wt[n][k] ----------------
__global__ __launch_bounds__(256) void prep_wt(const float* od1_wl, const float* od1_wr,
                                               const float* dt1_wl, const float* dt1_wr,
                                               const float* od2_wl, const float* od2_wr,
                                               const float* od3_wl, const float* od3_wr,
                                               const float* dt2_wl, const float* dt2_wr,
                                               ushort_t* wt1a, ushort_t* wt1b, ushort_t* wtod2,
                                               ushort_t* wtod3, ushort_t* wtdt2) {
    int i = blockIdx.x * 256 + threadIdx.x;
    const float* wl; const float* wr; ushort_t* dst; int q, KT;
    if (i < 32768)       { q = i;          KT = 256; wl = od1_wl; wr = od1_wr; dst = wt1a; }
    else if (i < 65536)  { q = i - 32768;  KT = 256; wl = dt1_wl; wr = dt1_wr; dst = wt1b; }
    else if (i < 90112)  { q = i - 65536;  KT = 192; wl = od2_wl; wr = od2_wr; dst = wtod2; }
    else if (i < 122880) { q = i - 90112;  KT = 256; wl = od3_wl; wr = od3_wr; dst = wtod3; }
    else if (i < 155648) { q = i - 122880; KT = 256; wl = dt2_wl; wr = dt2_wr; dst = wtdt2; }
    else return;
    int n = q / KT, k = q - n * KT;
    float v = (k < 128) ? wl[(size_t)k * 128 + n] : wr[(size_t)(k - 128) * 128 + n];
    dst[q] = f2bf(v);
}

// ---------------- XCD-sliced single-pass bucket fill ----------------
// slice s = blockIdx&7 owns dt nodes [s*3750,..) and od nodes [s*1250,..).
// Consecutive blockIdx round-robin across the 8 XCDs => all writers of a given
// bucket/counter line land on ONE XCD's L2 => each dirty line written back once.
// Correct regardless of the actual block->XCD mapping (only locality depends on it).
__global__ __launch_bounds__(256) void fill_sliced(const int* __restrict__ r1, const int* __restrict__ c1,
                                                   const int* __restrict__ rev_src, const int* __restrict__ rev_dst,
                                                   int* cnt_dt, ushort_t* srcs_dt,
                                                   int* cnt_od, ushort_t* srcs_od) {
    int s = blockIdx.x & 7;
    int chunk = blockIdx.x >> 3;
    int dtLo = s * (NDT / 8), dtHi = dtLo + (NDT / 8);
    int odLo = s * (NOD / 8), odHi = odLo + (NOD / 8);
    const int CH1 = (NE1 + NCHUNK - 1) / NCHUNK;
    const int CH2 = (NE2 + NCHUNK - 1) / NCHUNK;
    int e0 = chunk * CH1;
    int e1 = e0 + CH1 < NE1 ? e0 + CH1 : NE1;
    for (int i = e0 + threadIdx.x; i < e1; i += 256) {
        int d = c1[i];
        if (d >= dtLo && d < dtHi) {
            int p = atomicAdd(&cnt_dt[d], 1);
            if (p < CAP_DT) srcs_dt[d * CAP_DT + p] = (ushort_t)r1[i];
        }
    }
    e0 = chunk * CH2;
    e1 = e0 + CH2 < NE2 ? e0 + CH2 : NE2;
    for (int i = e0 + threadIdx.x; i < e1; i += 256) {
        int d = rev_dst[i];
        if (d >= odLo && d < odHi) {
            int p = atomicAdd(&cnt_od[d], 1);
            if (p < CAP_OD) srcs_od[d * CAP_OD + p] = (ushort_t)rev_src[i];
        }
    }
}

// ---------------- segment mean over bf16 rows (128 cols), bf16 out ----------------
__global__ __launch_bounds__(64) void seg_mean_bf(const ushort_t* __restrict__ X,
                                                  const int* __restrict__ cnt,
                                                  const ushort_t* __restrict__ srcs, int cap,
                                                  ushort_t* __restrict__ out) {
    int b = blockIdx.x;
    int t = threadIdx.x;             // 64 lanes, each owns cols 2t, 2t+1
    int deg = cnt[b];
    int n = deg < cap ? deg : cap;
    int start = b * cap;
    float a0 = 0.f, a1 = 0.f, b0 = 0.f, b1 = 0.f, c0 = 0.f, c1 = 0.f, d0 = 0.f, d1 = 0.f;
    int j = 0;
    for (; j + 3 < n; j += 4) {
        int s0 = srcs[start + j], s1 = srcs[start + j + 1];
        int s2 = srcs[start + j + 2], s3 = srcs[start + j + 3];
        uint_t v0 = *(const uint_t*)&X[(size_t)s0 * 128 + 2 * t];
        uint_t v1 = *(const uint_t*)&X[(size_t)s1 * 128 + 2 * t];
        uint_t v2 = *(const uint_t*)&X[(size_t)s2 * 128 + 2 * t];
        uint_t v3 = *(const uint_t*)&X[(size_t)s3 * 128 + 2 * t];
        a0 += bf2f(v0 & 0xffff); a1 += __uint_as_float(v0 & 0xffff0000u);
        b0 += bf2f(v1 & 0xffff); b1 += __uint_as_float(v1 & 0xffff0000u);
        c0 += bf2f(v2 & 0xffff); c1 += __uint_as_float(v2 & 0xffff0000u);
        d0 += bf2f(v3 & 0xffff); d1 += __uint_as_float(v3 & 0xffff0000u);
    }
    for (; j < n; j++) {
        uint_t v = *(const uint_t*)&X[(size_t)srcs[start + j] * 128 + 2 * t];
        a0 += bf2f(v & 0xffff); a1 += __uint_as_float(v & 0xffff0000u);
    }
    float inv = deg > 0 ? 1.f / (float)deg : 0.f;
    float s0 = ((a0 + b0) + (c0 + d0)) * inv;
    float s1 = ((a1 + b1) + (c1 + d1)) * inv;
    *(uint_t*)&out[(size_t)b * 128 + 2 * t] = (uint_t)f2bf(s0) | ((uint_t)f2bf(s1) << 16);
}

// ---------------- MFMA sage layer ----------------
template <bool DUAL>
__global__ __launch_bounds__(256) void sage_mfma(
    const ushort_t* __restrict__ A1, int K1,
    const ushort_t* __restrict__ A2, int K2,
    const ushort_t* __restrict__ Wta, const ushort_t* __restrict__ Wtb,
    const float* __restrict__ ba, const float* __restrict__ bb,
    ushort_t* __restrict__ outa, ushort_t* __restrict__ outb, int M) {
    __shared__ __align__(16) ushort_t As[32 * 264];
    __shared__ __align__(16) ushort_t Wsa[128 * 40];
    __shared__ __align__(16) ushort_t Wsb[DUAL ? 128 * 40 : 8];
    const int KT = K1 + K2;
    const int AST = KT + 8;
    int t = threadIdx.x;
    int lane = t & 63, wave = t >> 6;
    int quad = lane >> 4, l16 = lane & 15;
    int mtile = wave & 1, nquad = wave >> 1;
    int mb = blockIdx.x * 32;

    int c1n = 32 * (K1 >> 3);
    for (int c = t; c < c1n; c += 256) {
        int row = c / (K1 >> 3), k8 = (c % (K1 >> 3)) * 8;
        int m = mb + row; if (m >= M) m = M - 1;
        *(short8*)&As[row * AST + k8] = *(const short8*)&A1[(size_t)m * K1 + k8];
    }
    int c2n = 32 * (K2 >> 3);
    for (int c = t; c < c2n; c += 256) {
        int row = c / (K2 >> 3), k8 = (c % (K2 >> 3)) * 8;
        int m = mb + row; if (m >= M) m = M - 1;
        *(short8*)&As[row * AST + K1 + k8] = *(const short8*)&A2[(size_t)m * K2 + k8];
    }

    f32x4 acca[4] = {};
    f32x4 accb[4] = {};
    for (int kc = 0; kc < KT; kc += 32) {
        __syncthreads();
        for (int c = t; c < 512; c += 256) {
            int n = c >> 2, k8 = (c & 3) * 8;
            *(short8*)&Wsa[n * 40 + k8] = *(const short8*)&Wta[(size_t)n * KT + kc + k8];
            if (DUAL)
                *(short8*)&Wsb[n * 40 + k8] = *(const short8*)&Wtb[(size_t)n * KT + kc + k8];
        }
        __syncthreads();
        short8 af = *(const short8*)&As[(mtile * 16 + l16) * AST + kc + quad * 8];
#pragma unroll
        for (int nt = 0; nt < 4; nt++) {
            int n = (nquad * 4 + nt) * 16 + l16;
            short8 bfr = *(const short8*)&Wsa[n * 40 + quad * 8];
            acca[nt] = __builtin_amdgcn_mfma_f32_16x16x32_bf16(af, bfr, acca[nt], 0, 0, 0);
            if (DUAL) {
                short8 bfr2 = *(const short8*)&Wsb[n * 40 + quad * 8];
                accb[nt] = __builtin_amdgcn_mfma_f32_16x16x32_bf16(af, bfr2, accb[nt], 0, 0, 0);
            }
        }
    }
    int mrow = mb + mtile * 16 + quad * 4;
#pragma unroll
    for (int nt = 0; nt < 4; nt++) {
        int n = (nquad * 4 + nt) * 16 + l16;
        float bva = ba[n];
        float bvb = DUAL ? bb[n] : 0.f;
#pragma unroll
        for (int r = 0; r < 4; r++) {
            int m = mrow + r;
            if (m < M) {
                outa[(size_t)m * 128 + n] = f2bf(fmaxf(acca[nt][r] + bva, 0.f));
                if (DUAL) outb[(size_t)m * 128 + n] = f2bf(fmaxf(accb[nt][r] + bvb, 0.f));
            }
        }
    }
}

// ---------------- MFMA linear: out[M][64] bf16 = A[M][128] bf16 @ Wt[64][128] ----------------
__global__ __launch_bounds__(256) void lin_mfma(const ushort_t* __restrict__ A,
                                                const ushort_t* __restrict__ Wt,
                                                ushort_t* __restrict__ out, int M) {
    __shared__ __align__(16) ushort_t As[64 * 136];
    __shared__ __align__(16) ushort_t Ws[64 * 40];
    int t = threadIdx.x;
    int lane = t & 63, wave = t >> 6;
    int quad = lane >> 4, l16 = lane & 15;
    int mb = blockIdx.x * 64;
    for (int c = t; c < 1024; c += 256) {
        int row = c >> 4, k8 = (c & 15) * 8;
        int m = mb + row; if (m >= M) m = M - 1;
        *(short8*)&As[row * 136 + k8] = *(const short8*)&A[(size_t)m * 128 + k8];
    }
    f32x4 acc[4] = {};
    for (int kc = 0; kc < 128; kc += 32) {
        __syncthreads();
        for (int c = t; c < 256; c += 256) {
            int n = c >> 2, k8 = (c & 3) * 8;
            *(short8*)&Ws[n * 40 + k8] = *(const short8*)&Wt[(size_t)n * 128 + kc + k8];
        }
        __syncthreads();
        short8 af = *(const short8*)&As[(wave * 16 + l16) * 136 + kc + quad * 8];
#pragma unroll
        for (int nt = 0; nt < 4; nt++) {
            short8 bfr = *(const short8*)&Ws[(nt * 16 + l16) * 40 + quad * 8];
            acc[nt] = __builtin_amdgcn_mfma_f32_16x16x32_bf16(af, bfr, acc[nt], 0, 0, 0);
        }
    }
    int mrow = mb + wave * 16 + quad * 4;
#pragma unroll
    for (int nt = 0; nt < 4; nt++) {
        int n = nt * 16 + l16;
#pragma unroll
        for (int r = 0; r < 4; r++) {
            int m = mrow + r;
            if (m < M) out[(size_t)m * 64 + n] = f2bf(acc[nt][r]);
        }
    }
}

// ---------------- decoder weight fusion (bf16 transposed outputs) ----------------
__global__ __launch_bounds__(256) void fuse_dec(const float* __restrict__ od_lw, const float* __restrict__ od_lb,
                                                const float* __restrict__ dt_lw, const float* __restrict__ dt_lb,
                                                const float* __restrict__ w1, const float* __restrict__ b1,
                                                ushort_t* wodt, ushort_t* wdtt, float* bfuse) {
    int i = blockIdx.x * 256 + threadIdx.x;
    if (i < 8192) {
        int r = i >> 6, p = i & 63;
        float s = 0.f;
        for (int j = 0; j < 64; j++) s = fmaf(od_lw[r * 64 + j], w1[j * 64 + p], s);
        wodt[p * 128 + r] = f2bf(s);
    } else if (i < 16384) {
        int q = i - 8192, r = q >> 6, p = q & 63;
        float s = 0.f;
        for (int j = 0; j < 64; j++) s = fmaf(dt_lw[r * 64 + j], w1[(64 + j) * 64 + p], s);
        wdtt[p * 128 + r] = f2bf(s);
    } else if (i < 16448) {
        int p = i - 16384;
        float s = b1[p];
        for (int j = 0; j < 64; j++) {
            s = fmaf(od_lb[j], w1[j * 64 + p], s);
            s = fmaf(dt_lb[j], w1[(64 + j) * 64 + p], s);
        }
        bfuse[p] = s;
    }
}

// ---------------- decoder: bf16 P gathers, f32 output ----------------
__global__ __launch_bounds__(256) void decode(const ushort_t* __restrict__ P_od, const ushort_t* __restrict__ P_dt,
                                              const int* __restrict__ el_src, const int* __restrict__ el_dst,
                                              const float* __restrict__ bfuse, const float* __restrict__ w2,
                                              const float* __restrict__ b2v, float* __restrict__ out) {
    __shared__ __align__(16) float bf[64];
    __shared__ __align__(16) float w2s[64];
    int t = threadIdx.x;
    if (t < 64) { bf[t] = bfuse[t]; w2s[t] = w2[t]; }
    __syncthreads();
    int e = blockIdx.x * 256 + t;
    if (e >= NEL) return;
    const uint4* po = (const uint4*)(P_od + (size_t)el_src[e] * 64);
    const uint4* pt = (const uint4*)(P_dt + (size_t)el_dst[e] * 64);
    float acc = 0.f;
#pragma unroll
    for (int c = 0; c < 8; c++) {
        uint4 a = po[c], b = pt[c];
        const uint_t* au = (const uint_t*)&a;
        const uint_t* bu = (const uint_t*)&b;
#pragma unroll
        for (int j = 0; j < 4; j++) {
            int idx = c * 8 + j * 2;
            float lo = bf2f(au[j] & 0xffff) + bf2f(bu[j] & 0xffff) + bf[idx];
            float hi = __uint_as_float(au[j] & 0xffff0000u) + __uint_as_float(bu[j] & 0xffff0000u) + bf[idx + 1];
            acc = fmaf(fmaxf(lo, 0.f), w2s[idx], acc);
            acc = fmaf(fmaxf(hi, 0.f), w2s[idx + 1], acc);
        }
    }
    float z = acc + b2v[0];
    out[e] = 1.f / (1.f + __expf(-z));
}

// ---------------- launch ----------------
extern "C" void kernel_launch(void* const* d_in, const int* in_sizes, int n_in,
                              void* d_out, int out_size, void* d_ws, size_t ws_size,
                              hipStream_t stream) {
    float* W = (float*)d_ws;
    ushort_t* U = (ushort_t*)(W + F_ENDF);
    int* I = (int*)(U + U_END);

    const float* x_dt   = (const float*)d_in[0];
    const float* x_od   = (const float*)d_in[1];
    const int* ei       = (const int*)d_in[2];
    const int* r1 = ei;
    const int* c1 = ei + NE1;
    const int* rev_src  = (const int*)d_in[3];
    const int* rev_dst  = (const int*)d_in[4];
    const int* el_src   = (const int*)d_in[5];
    const int* el_dst   = (const int*)d_in[6];
    const float* od1_wl = (const float*)d_in[7],  *od1_wr = (const float*)d_in[8],  *od1_b = (const float*)d_in[9];
    const float* od2_wl = (const float*)d_in[10], *od2_wr = (const float*)d_in[11], *od2_b = (const float*)d_in[12];
    const float* od3_wl = (const float*)d_in[13], *od3_wr = (const float*)d_in[14], *od3_b = (const float*)d_in[15];
    const float* od_lw  = (const float*)d_in[16], *od_lb  = (const float*)d_in[17];
    const float* dt1_wl = (const float*)d_in[18], *dt1_wr = (const float*)d_in[19], *dt1_b = (const float*)d_in[20];
    const float* dt2_wl = (const float*)d_in[21], *dt2_wr = (const float*)d_in[22], *dt2_b = (const float*)d_in[23];
    const float* dt_lw  = (const float*)d_in[24], *dt_lb  = (const float*)d_in[25];
    const float* dec_w1 = (const float*)d_in[26], *dec_b1 = (const float*)d_in[27];
    const float* dec_w2 = (const float*)d_in[28], *dec_b2 = (const float*)d_in[29];

    hipMemsetAsync(I + I_CNT_DT, 0, (NDT + NOD) * sizeof(int), stream);

    conv_bf<<<((NDT * 128 + NOD * 64) / 4 + 255) / 256, 256, 0, stream>>>(x_dt, x_od, U + U_XDT, U + U_XOD);
    prep_wt<<<(155648 + 255) / 256, 256, 0, stream>>>(od1_wl, od1_wr, dt1_wl, dt1_wr, od2_wl, od2_wr,
                                                      od3_wl, od3_wr, dt2_wl, dt2_wr,
                                                      U + U_WT1A, U + U_WT1B, U + U_WTOD2, U + U_WTOD3, U + U_WTDT2);
    // XCD-sliced single-pass bucket fill
    fill_sliced<<<NCHUNK * 8, 256, 0, stream>>>(r1, c1, rev_src, rev_dst,
                                                I + I_CNT_DT, U + U_SRC_DT,
                                                I + I_CNT_OD, U + U_SRC_OD);
    fuse_dec<<<(16448 + 255) / 256, 256, 0, stream>>>(od_lw, od_lb, dt_lw, dt_lb, dec_w1, dec_b1,
                                                      U + U_WLODT, U + U_WLDTT, W + F_BFUSE);

    // agg_x = segmean(x_dt)
    seg_mean_bf<<<NDT, 64, 0, stream>>>(U + U_XDT, I + I_CNT_DT, U + U_SRC_DT, CAP_DT, U + U_AGGX);
    // h, d1 (dual MFMA)
    sage_mfma<true><<<(NDT + 31) / 32, 256, 0, stream>>>(U + U_AGGX, 128, U + U_XDT, 128,
                                                         U + U_WT1A, U + U_WT1B, od1_b, dt1_b,
                                                         U + U_H, U + U_D1, NDT);
    // agg_h = segmean(h) over rev graph
    seg_mean_bf<<<NOD, 64, 0, stream>>>(U + U_H, I + I_CNT_OD, U + U_SRC_OD, CAP_OD, U + U_AGGH);
    // od2
    sage_mfma<false><<<(NOD + 31) / 32, 256, 0, stream>>>(U + U_AGGH, 128, U + U_XOD, 64,
                                                          U + U_WTOD2, nullptr, od2_b, nullptr,
                                                          U + U_OD2, nullptr, NOD);
    // od3
    sage_mfma<false><<<(NOD + 31) / 32, 256, 0, stream>>>(U + U_AGGH, 128, U + U_OD2, 128,
                                                          U + U_WTOD3, nullptr, od3_b, nullptr,
                                                          U + U_OD3, nullptr, NOD);
    // agg_d = segmean(d1)
    seg_mean_bf<<<NDT, 64, 0, stream>>>(U + U_D1, I + I_CNT_DT, U + U_SRC_DT, CAP_DT, U + U_AGGX);
    // d2
    sage_mfma<false><<<(NDT + 31) / 32, 256, 0, stream>>>(U + U_AGGX, 128, U + U_D1, 128,
                                                          U + U_WTDT2, nullptr, dt2_b, nullptr,
                                                          U + U_H, nullptr, NDT);
    // P tables (bf16)
    lin_mfma<<<(NOD + 63) / 64, 256, 0, stream>>>(U + U_OD3, U + U_WLODT, U + U_POD, NOD);
    lin_mfma<<<(NDT + 63) / 64, 256, 0, stream>>>(U + U_H, U + U_WLDTT, U + U_PDT, NDT);
    // decoder
    decode<<<(NEL + 255) / 256, 256, 0, stream>>>(U + U_POD, U + U_PDT, el_src, el_dst,
                                                  W + F_BFUSE, dec_w2, dec_b2, (float*)d_out);
}

// Round 11
// 299.729 us; speedup vs baseline: 1.0590x; 1.0590x over previous
//
#include <hip/hip_runtime.h>
#include <hip/hip_bf16.h>

#define NDT 30000
#define NOD 10000
#define NE1 500000
#define NE2 300000
#define NEL 200000
#define CAP_DT 64
#define CAP_OD 96

typedef unsigned short ushort_t;
typedef unsigned int uint_t;
typedef __attribute__((ext_vector_type(8))) short short8;
typedef __attribute__((ext_vector_type(4))) float f32x4;

// ---------------- workspace layout ----------------
// float region
static constexpr size_t F_BFUSE = 0;                          // 64
static constexpr size_t F_ENDF  = 64;
// ushort region (base = (ushort_t*)(W + F_ENDF))
static constexpr size_t U_XDT    = 0;                          // 30000*128
static constexpr size_t U_XOD    = U_XDT + (size_t)NDT * 128;  // 10000*64
static constexpr size_t U_AGGX   = U_XOD + (size_t)NOD * 64;   // 30000*128 (agg_x, later agg_d)
static constexpr size_t U_H      = U_AGGX + (size_t)NDT * 128; // h, later d2
static constexpr size_t U_D1     = U_H + (size_t)NDT * 128;
static constexpr size_t U_AGGH   = U_D1 + (size_t)NDT * 128;   // 10000*128
static constexpr size_t U_OD2    = U_AGGH + (size_t)NOD * 128;
static constexpr size_t U_OD3    = U_OD2 + (size_t)NOD * 128;
static constexpr size_t U_WT1A   = U_OD3 + (size_t)NOD * 128;  // 128*256
static constexpr size_t U_WT1B   = U_WT1A + 32768;
static constexpr size_t U_WTOD2  = U_WT1B + 32768;             // 128*192
static constexpr size_t U_WTOD3  = U_WTOD2 + 24576;
static constexpr size_t U_WTDT2  = U_WTOD3 + 32768;
static constexpr size_t U_WLODT  = U_WTDT2 + 32768;            // 64*128
static constexpr size_t U_WLDTT  = U_WLODT + 8192;
static constexpr size_t U_POD    = U_WLDTT + 8192;             // 10000*64 bf16
static constexpr size_t U_PDT    = U_POD + (size_t)NOD * 64;   // 30000*64 bf16
static constexpr size_t U_SRC_DT = U_PDT + (size_t)NDT * 64;   // 30000*64 ushort
static constexpr size_t U_SRC_OD = U_SRC_DT + (size_t)NDT * CAP_DT; // 10000*96 ushort
static constexpr size_t U_END    = U_SRC_OD + (size_t)NOD * CAP_OD;
// int region (base = int* after U; memset covers both cnt arrays)
static constexpr size_t I_CNT_DT = 0;        // 30000
static constexpr size_t I_CNT_OD = 30000;    // 10000

__device__ __forceinline__ ushort_t f2bf(float f) {
    uint_t u = __float_as_uint(f);
    return (ushort_t)((u + 0x7fffu + ((u >> 16) & 1u)) >> 16);
}
__device__ __forceinline__ float bf2f(uint_t lo16) { return __uint_as_float(lo16 << 16); }

// ---------------- conversions: x tables -> bf16 ----------------
__global__ __launch_bounds__(256) void conv_bf(const float* __restrict__ x_dt, const float* __restrict__ x_od,
                                               ushort_t* __restrict__ xdt_bf, ushort_t* __restrict__ xod_bf) {
    int i = blockIdx.x * 256 + threadIdx.x;
    size_t i4 = (size_t)i * 4;
    const size_t n_dt = (size_t)NDT * 128, n_od = (size_t)NOD * 64;
    if (i4 < n_dt) {
        float4 v = *(const float4*)(x_dt + i4);
        ushort4 o = { f2bf(v.x), f2bf(v.y), f2bf(v.z), f2bf(v.w) };
        *(ushort4*)(xdt_bf + i4) = o;
    } else if (i4 - n_dt < n_od) {
        size_t j = i4 - n_dt;
        float4 v = *(const float4*)(x_od + j);
        ushort4 o = { f2bf(v.x), f2bf(v.y), f2bf(v.z), f2bf(v.w) };
        *(ushort4*)(xod_bf + j) = o;
    }
}

// ---------------- prep: combined transposed bf16 weights Wt[n][k] ----------------
__global__ __launch_bounds__(256) void prep_wt(const float* od1_wl, const float* od1_wr,
                                               const float* dt1_wl, const float* dt1_wr,
                                               const float* od2_wl, const float* od2_wr,
                                               const float* od3_wl, const float* od3_wr,
                                               const float* dt2_wl, const float* dt2_wr,
                                               ushort_t* wt1a, ushort_t* wt1b, ushort_t* wtod2,
                                               ushort_t* wtod3, ushort_t* wtdt2) {
    int i = blockIdx.x * 256 + threadIdx.x;
    const float* wl; const float* wr; ushort_t* dst; int q, KT;
    if (i < 32768)       { q = i;          KT = 256; wl = od1_wl; wr = od1_wr; dst = wt1a; }
    else if (i < 65536)  { q = i - 32768;  KT = 256; wl = dt1_wl; wr = dt1_wr; dst = wt1b; }
    else if (i < 90112)  { q = i - 65536;  KT = 192; wl = od2_wl; wr = od2_wr; dst = wtod2; }
    else if (i < 122880) { q = i - 90112;  KT = 256; wl = od3_wl; wr = od3_wr; dst = wtod3; }
    else if (i < 155648) { q = i - 122880; KT = 256; wl = dt2_wl; wr = dt2_wr; dst = wtdt2; }
    else return;
    int n = q / KT, k = q - n * KT;
    float v = (k < 128) ? wl[(size_t)k * 128 + n] : wr[(size_t)(k - 128) * 128 + n];
    dst[q] = f2bf(v);
}

// ---------------- direct CSR fill: fixed-capacity buckets, single pass ----------------
// (R10 post-mortem: XCD-sliced variant cut WRITE_SIZE 41->27MB but 8x edge re-read
//  + 1/8 parallelism made it slower; 2B-random-scatter write floor ~= stores*32B sector.)
__global__ __launch_bounds__(256) void fill_direct(const int* __restrict__ r1, const int* __restrict__ c1,
                                                   const int* __restrict__ rev_src, const int* __restrict__ rev_dst,
                                                   int* cnt_dt, ushort_t* srcs_dt,
                                                   int* cnt_od, ushort_t* srcs_od) {
    int b = (blockIdx.x * 256 + threadIdx.x) * 4;
    if (b + 3 < NE1) {
        int4 d = *(const int4*)(c1 + b);
        int4 s = *(const int4*)(r1 + b);
        int p0 = atomicAdd(&cnt_dt[d.x], 1);
        int p1 = atomicAdd(&cnt_dt[d.y], 1);
        int p2 = atomicAdd(&cnt_dt[d.z], 1);
        int p3 = atomicAdd(&cnt_dt[d.w], 1);
        if (p0 < CAP_DT) srcs_dt[d.x * CAP_DT + p0] = (ushort_t)s.x;
        if (p1 < CAP_DT) srcs_dt[d.y * CAP_DT + p1] = (ushort_t)s.y;
        if (p2 < CAP_DT) srcs_dt[d.z * CAP_DT + p2] = (ushort_t)s.z;
        if (p3 < CAP_DT) srcs_dt[d.w * CAP_DT + p3] = (ushort_t)s.w;
    } else {
        for (int i = b; i < NE1; i++) {
            int p = atomicAdd(&cnt_dt[c1[i]], 1);
            if (p < CAP_DT) srcs_dt[c1[i] * CAP_DT + p] = (ushort_t)r1[i];
        }
    }
    if (b + 3 < NE2) {
        int4 d = *(const int4*)(rev_dst + b);
        int4 s = *(const int4*)(rev_src + b);
        int p0 = atomicAdd(&cnt_od[d.x], 1);
        int p1 = atomicAdd(&cnt_od[d.y], 1);
        int p2 = atomicAdd(&cnt_od[d.z], 1);
        int p3 = atomicAdd(&cnt_od[d.w], 1);
        if (p0 < CAP_OD) srcs_od[d.x * CAP_OD + p0] = (ushort_t)s.x;
        if (p1 < CAP_OD) srcs_od[d.y * CAP_OD + p1] = (ushort_t)s.y;
        if (p2 < CAP_OD) srcs_od[d.z * CAP_OD + p2] = (ushort_t)s.z;
        if (p3 < CAP_OD) srcs_od[d.w * CAP_OD + p3] = (ushort_t)s.w;
    } else if (b < NE2) {
        for (int i = b; i < NE2; i++) {
            int p = atomicAdd(&cnt_od[rev_dst[i]], 1);
            if (p < CAP_OD) srcs_od[rev_dst[i] * CAP_OD + p] = (ushort_t)rev_src[i];
        }
    }
}

// ---------------- segment mean over bf16 rows (128 cols), bf16 out ----------------
// one node per 64-thread block (measured best: R7/R10 post-mortems); ILP-8 gather.
__global__ __launch_bounds__(64) void seg_mean_bf(const ushort_t* __restrict__ X,
                                                  const int* __restrict__ cnt,
                                                  const ushort_t* __restrict__ srcs, int cap,
                                                  ushort_t* __restrict__ out) {
    int b = blockIdx.x;
    int t = threadIdx.x;             // 64 lanes, each owns cols 2t, 2t+1
    int deg = cnt[b];
    int n = deg < cap ? deg : cap;
    int start = b * cap;
    float lo[8] = {}, hi[8] = {};
    int j = 0;
    for (; j + 7 < n; j += 8) {
        uint_t v[8];
#pragma unroll
        for (int u = 0; u < 8; u++) {
            int s = srcs[start + j + u];
            v[u] = *(const uint_t*)&X[(size_t)s * 128 + 2 * t];
        }
#pragma unroll
        for (int u = 0; u < 8; u++) {
            lo[u] += bf2f(v[u] & 0xffff);
            hi[u] += __uint_as_float(v[u] & 0xffff0000u);
        }
    }
    for (; j < n; j++) {
        uint_t v = *(const uint_t*)&X[(size_t)srcs[start + j] * 128 + 2 * t];
        lo[0] += bf2f(v & 0xffff);
        hi[0] += __uint_as_float(v & 0xffff0000u);
    }
    float inv = deg > 0 ? 1.f / (float)deg : 0.f;
    float s0 = (((lo[0] + lo[1]) + (lo[2] + lo[3])) + ((lo[4] + lo[5]) + (lo[6] + lo[7]))) * inv;
    float s1 = (((hi[0] + hi[1]) + (hi[2] + hi[3])) + ((hi[4] + hi[5]) + (hi[6] + hi[7]))) * inv;
    *(uint_t*)&out[(size_t)b * 128 + 2 * t] = (uint_t)f2bf(s0) | ((uint_t)f2bf(s1) << 16);
}

// ---------------- MFMA sage layer ----------------
template <bool DUAL>
__global__ __launch_bounds__(256) void sage_mfma(
    const ushort_t* __restrict__ A1, int K1,
    const ushort_t* __restrict__ A2, int K2,
    const ushort_t* __restrict__ Wta, const ushort_t* __restrict__ Wtb,
    const float* __restrict__ ba, const float* __restrict__ bb,
    ushort_t* __restrict__ outa, ushort_t* __restrict__ outb, int M) {
    __shared__ __align__(16) ushort_t As[32 * 264];
    __shared__ __align__(16) ushort_t Wsa[128 * 40];
    __shared__ __align__(16) ushort_t Wsb[DUAL ? 128 * 40 : 8];
    const int KT = K1 + K2;
    const int AST = KT + 8;
    int t = threadIdx.x;
    int lane = t & 63, wave = t >> 6;
    int quad = lane >> 4, l16 = lane & 15;
    int mtile = wave & 1, nquad = wave >> 1;
    int mb = blockIdx.x * 32;

    int c1n = 32 * (K1 >> 3);
    for (int c = t; c < c1n; c += 256) {
        int row = c / (K1 >> 3), k8 = (c % (K1 >> 3)) * 8;
        int m = mb + row; if (m >= M) m = M - 1;
        *(short8*)&As[row * AST + k8] = *(const short8*)&A1[(size_t)m * K1 + k8];
    }
    int c2n = 32 * (K2 >> 3);
    for (int c = t; c < c2n; c += 256) {
        int row = c / (K2 >> 3), k8 = (c % (K2 >> 3)) * 8;
        int m = mb + row; if (m >= M) m = M - 1;
        *(short8*)&As[row * AST + K1 + k8] = *(const short8*)&A2[(size_t)m * K2 + k8];
    }

    f32x4 acca[4] = {};
    f32x4 accb[4] = {};
    for (int kc = 0; kc < KT; kc += 32) {
        __syncthreads();
        for (int c = t; c < 512; c += 256) {
            int n = c >> 2, k8 = (c & 3) * 8;
            *(short8*)&Wsa[n * 40 + k8] = *(const short8*)&Wta[(size_t)n * KT + kc + k8];
            if (DUAL)
                *(short8*)&Wsb[n * 40 + k8] = *(const short8*)&Wtb[(size_t)n * KT + kc + k8];
        }
        __syncthreads();
        short8 af = *(const short8*)&As[(mtile * 16 + l16) * AST + kc + quad * 8];
#pragma unroll
        for (int nt = 0; nt < 4; nt++) {
            int n = (nquad * 4 + nt) * 16 + l16;
            short8 bfr = *(const short8*)&Wsa[n * 40 + quad * 8];
            acca[nt] = __builtin_amdgcn_mfma_f32_16x16x32_bf16(af, bfr, acca[nt], 0, 0, 0);
            if (DUAL) {
                short8 bfr2 = *(const short8*)&Wsb[n * 40 + quad * 8];
                accb[nt] = __builtin_amdgcn_mfma_f32_16x16x32_bf16(af, bfr2, accb[nt], 0, 0, 0);
            }
        }
    }
    int mrow = mb + mtile * 16 + quad * 4;
#pragma unroll
    for (int nt = 0; nt < 4; nt++) {
        int n = (nquad * 4 + nt) * 16 + l16;
        float bva = ba[n];
        float bvb = DUAL ? bb[n] : 0.f;
#pragma unroll
        for (int r = 0; r < 4; r++) {
            int m = mrow + r;
            if (m < M) {
                outa[(size_t)m * 128 + n] = f2bf(fmaxf(acca[nt][r] + bva, 0.f));
                if (DUAL) outb[(size_t)m * 128 + n] = f2bf(fmaxf(accb[nt][r] + bvb, 0.f));
            }
        }
    }
}

// ---------------- MFMA linear: out[M][64] bf16 = A[M][128] bf16 @ Wt[64][128] ----------------
__global__ __launch_bounds__(256) void lin_mfma(const ushort_t* __restrict__ A,
                                                const ushort_t* __restrict__ Wt,
                                                ushort_t* __restrict__ out, int M) {
    __shared__ __align__(16) ushort_t As[64 * 136];
    __shared__ __align__(16) ushort_t Ws[64 * 40];
    int t = threadIdx.x;
    int lane = t & 63, wave = t >> 6;
    int quad = lane >> 4, l16 = lane & 15;
    int mb = blockIdx.x * 64;
    for (int c = t; c < 1024; c += 256) {
        int row = c >> 4, k8 = (c & 15) * 8;
        int m = mb + row; if (m >= M) m = M - 1;
        *(short8*)&As[row * 136 + k8] = *(const short8*)&A[(size_t)m * 128 + k8];
    }
    f32x4 acc[4] = {};
    for (int kc = 0; kc < 128; kc += 32) {
        __syncthreads();
        for (int c = t; c < 256; c += 256) {
            int n = c >> 2, k8 = (c & 3) * 8;
            *(short8*)&Ws[n * 40 + k8] = *(const short8*)&Wt[(size_t)n * 128 + kc + k8];
        }
        __syncthreads();
        short8 af = *(const short8*)&As[(wave * 16 + l16) * 136 + kc + quad * 8];
#pragma unroll
        for (int nt = 0; nt < 4; nt++) {
            short8 bfr = *(const short8*)&Ws[(nt * 16 + l16) * 40 + quad * 8];
            acc[nt] = __builtin_amdgcn_mfma_f32_16x16x32_bf16(af, bfr, acc[nt], 0, 0, 0);
        }
    }
    int mrow = mb + wave * 16 + quad * 4;
#pragma unroll
    for (int nt = 0; nt < 4; nt++) {
        int n = nt * 16 + l16;
#pragma unroll
        for (int r = 0; r < 4; r++) {
            int m = mrow + r;
            if (m < M) out[(size_t)m * 64 + n] = f2bf(acc[nt][r]);
        }
    }
}

// ---------------- decoder weight fusion (bf16 transposed outputs) ----------------
__global__ __launch_bounds__(256) void fuse_dec(const float* __restrict__ od_lw, const float* __restrict__ od_lb,
                                                const float* __restrict__ dt_lw, const float* __restrict__ dt_lb,
                                                const float* __restrict__ w1, const float* __restrict__ b1,
                                                ushort_t* wodt, ushort_t* wdtt, float* bfuse) {
    int i = blockIdx.x * 256 + threadIdx.x;
    if (i < 8192) {
        int r = i >> 6, p = i & 63;
        float s = 0.f;
        for (int j = 0; j < 64; j++) s = fmaf(od_lw[r * 64 + j], w1[j * 64 + p], s);
        wodt[p * 128 + r] = f2bf(s);
    } else if (i < 16384) {
        int q = i - 8192, r = q >> 6, p = q & 63;
        float s = 0.f;
        for (int j = 0; j < 64; j++) s = fmaf(dt_lw[r * 64 + j], w1[(64 + j) * 64 + p], s);
        wdtt[p * 128 + r] = f2bf(s);
    } else if (i < 16448) {
        int p = i - 16384;
        float s = b1[p];
        for (int j = 0; j < 64; j++) {
            s = fmaf(od_lb[j], w1[j * 64 + p], s);
            s = fmaf(dt_lb[j], w1[(64 + j) * 64 + p], s);
        }
        bfuse[p] = s;
    }
}

// ---------------- decoder: bf16 P gathers, f32 output ----------------
__global__ __launch_bounds__(256) void decode(const ushort_t* __restrict__ P_od, const ushort_t* __restrict__ P_dt,
                                              const int* __restrict__ el_src, const int* __restrict__ el_dst,
                                              const float* __restrict__ bfuse, const float* __restrict__ w2,
                                              const float* __restrict__ b2v, float* __restrict__ out) {
    __shared__ __align__(16) float bf[64];
    __shared__ __align__(16) float w2s[64];
    int t = threadIdx.x;
    if (t < 64) { bf[t] = bfuse[t]; w2s[t] = w2[t]; }
    __syncthreads();
    int e = blockIdx.x * 256 + t;
    if (e >= NEL) return;
    const uint4* po = (const uint4*)(P_od + (size_t)el_src[e] * 64);
    const uint4* pt = (const uint4*)(P_dt + (size_t)el_dst[e] * 64);
    float acc = 0.f;
#pragma unroll
    for (int c = 0; c < 8; c++) {
        uint4 a = po[c], b = pt[c];
        const uint_t* au = (const uint_t*)&a;
        const uint_t* bu = (const uint_t*)&b;
#pragma unroll
        for (int j = 0; j < 4; j++) {
            int idx = c * 8 + j * 2;
            float lo = bf2f(au[j] & 0xffff) + bf2f(bu[j] & 0xffff) + bf[idx];
            float hi = __uint_as_float(au[j] & 0xffff0000u) + __uint_as_float(bu[j] & 0xffff0000u) + bf[idx + 1];
            acc = fmaf(fmaxf(lo, 0.f), w2s[idx], acc);
            acc = fmaf(fmaxf(hi, 0.f), w2s[idx + 1], acc);
        }
    }
    float z = acc + b2v[0];
    out[e] = 1.f / (1.f + __expf(-z));
}

// ---------------- launch ----------------
extern "C" void kernel_launch(void* const* d_in, const int* in_sizes, int n_in,
                              void* d_out, int out_size, void* d_ws, size_t ws_size,
                              hipStream_t stream) {
    float* W = (float*)d_ws;
    ushort_t* U = (ushort_t*)(W + F_ENDF);
    int* I = (int*)(U + U_END);

    const float* x_dt   = (const float*)d_in[0];
    const float* x_od   = (const float*)d_in[1];
    const int* ei       = (const int*)d_in[2];
    const int* r1 = ei;
    const int* c1 = ei + NE1;
    const int* rev_src  = (const int*)d_in[3];
    const int* rev_dst  = (const int*)d_in[4];
    const int* el_src   = (const int*)d_in[5];
    const int* el_dst   = (const int*)d_in[6];
    const float* od1_wl = (const float*)d_in[7],  *od1_wr = (const float*)d_in[8],  *od1_b = (const float*)d_in[9];
    const float* od2_wl = (const float*)d_in[10], *od2_wr = (const float*)d_in[11], *od2_b = (const float*)d_in[12];
    const float* od3_wl = (const float*)d_in[13], *od3_wr = (const float*)d_in[14], *od3_b = (const float*)d_in[15];
    const float* od_lw  = (const float*)d_in[16], *od_lb  = (const float*)d_in[17];
    const float* dt1_wl = (const float*)d_in[18], *dt1_wr = (const float*)d_in[19], *dt1_b = (const float*)d_in[20];
    const float* dt2_wl = (const float*)d_in[21], *dt2_wr = (const float*)d_in[22], *dt2_b = (const float*)d_in[23];
    const float* dt_lw  = (const float*)d_in[24], *dt_lb  = (const float*)d_in[25];
    const float* dec_w1 = (const float*)d_in[26], *dec_b1 = (const float*)d_in[27];
    const float* dec_w2 = (const float*)d_in[28], *dec_b2 = (const float*)d_in[29];

    hipMemsetAsync(I + I_CNT_DT, 0, (NDT + NOD) * sizeof(int), stream);

    conv_bf<<<((NDT * 128 + NOD * 64) / 4 + 255) / 256, 256, 0, stream>>>(x_dt, x_od, U + U_XDT, U + U_XOD);
    prep_wt<<<(155648 + 255) / 256, 256, 0, stream>>>(od1_wl, od1_wr, dt1_wl, dt1_wr, od2_wl, od2_wr,
                                                      od3_wl, od3_wr, dt2_wl, dt2_wr,
                                                      U + U_WT1A, U + U_WT1B, U + U_WTOD2, U + U_WTOD3, U + U_WTDT2);
    // single-pass fixed-capacity CSR
    fill_direct<<<(NE1 / 4 + 255) / 256, 256, 0, stream>>>(r1, c1, rev_src, rev_dst,
                                                           I + I_CNT_DT, U + U_SRC_DT,
                                                           I + I_CNT_OD, U + U_SRC_OD);
    fuse_dec<<<(16448 + 255) / 256, 256, 0, stream>>>(od_lw, od_lb, dt_lw, dt_lb, dec_w1, dec_b1,
                                                      U + U_WLODT, U + U_WLDTT, W + F_BFUSE);

    // agg_x = segmean(x_dt)
    seg_mean_bf<<<NDT, 64, 0, stream>>>(U + U_XDT, I + I_CNT_DT, U + U_SRC_DT, CAP_DT, U + U_AGGX);
    // h, d1 (dual MFMA)
    sage_mfma<true><<<(NDT + 31) / 32, 256, 0, stream>>>(U + U_AGGX, 128, U + U_XDT, 128,
                                                         U + U_WT1A, U + U_WT1B, od1_b, dt1_b,
                                                         U + U_H, U + U_D1, NDT);
    // agg_h = segmean(h) over rev graph
    seg_mean_bf<<<NOD, 64, 0, stream>>>(U + U_H, I + I_CNT_OD, U + U_SRC_OD, CAP_OD, U + U_AGGH);
    // od2
    sage_mfma<false><<<(NOD + 31) / 32, 256, 0, stream>>>(U + U_AGGH, 128, U + U_XOD, 64,
                                                          U + U_WTOD2, nullptr, od2_b, nullptr,
                                                          U + U_OD2, nullptr, NOD);
    // od3
    sage_mfma<false><<<(NOD + 31) / 32, 256, 0, stream>>>(U + U_AGGH, 128, U + U_OD2, 128,
                                                          U + U_WTOD3, nullptr, od3_b, nullptr,
                                                          U + U_OD3, nullptr, NOD);
    // agg_d = segmean(d1)
    seg_mean_bf<<<NDT, 64, 0, stream>>>(U + U_D1, I + I_CNT_DT, U + U_SRC_DT, CAP_DT, U + U_AGGX);
    // d2
    sage_mfma<false><<<(NDT + 31) / 32, 256, 0, stream>>>(U + U_AGGX, 128, U + U_D1, 128,
                                                          U + U_WTDT2, nullptr, dt2_b, nullptr,
                                                          U + U_H, nullptr, NDT);
    // P tables (bf16)
    lin_mfma<<<(NOD + 63) / 64, 256, 0, stream>>>(U + U_OD3, U + U_WLODT, U + U_POD, NOD);
    lin_mfma<<<(NDT + 63) / 64, 256, 0, stream>>>(U + U_H, U + U_WLDTT, U + U_PDT, NDT);
    // decoder
    decode<<<(NEL + 255) / 256, 256, 0, stream>>>(U + U_POD, U + U_PDT, el_src, el_dst,
                                                  W + F_BFUSE, dec_w2, dec_b2, (float*)d_out);
}

// Round 12
// 295.297 us; speedup vs baseline: 1.0749x; 1.0150x over previous
//
#include <hip/hip_runtime.h>
#include <hip/hip_bf16.h>

#define NDT 30000
#define NOD 10000
#define NE1 500000
#define NE2 300000
#define NEL 200000
#define CAP_DT 64
#define CAP_OD 96

typedef unsigned short ushort_t;
typedef unsigned int uint_t;
typedef __attribute__((ext_vector_type(8))) short short8;
typedef __attribute__((ext_vector_type(4))) float f32x4;

// ---------------- workspace layout ----------------
// float region
static constexpr size_t F_BFUSE = 0;                          // 64
static constexpr size_t F_ENDF  = 64;
// ushort region (base = (ushort_t*)(W + F_ENDF))
static constexpr size_t U_XDT    = 0;                          // 30000*128
static constexpr size_t U_XOD    = U_XDT + (size_t)NDT * 128;  // 10000*64
static constexpr size_t U_AGGX   = U_XOD + (size_t)NOD * 64;   // 30000*128 (agg_x, later agg_d)
static constexpr size_t U_H      = U_AGGX + (size_t)NDT * 128; // h, later d2
static constexpr size_t U_D1     = U_H + (size_t)NDT * 128;
static constexpr size_t U_AGGH   = U_D1 + (size_t)NDT * 128;   // 10000*128
static constexpr size_t U_OD2    = U_AGGH + (size_t)NOD * 128;
static constexpr size_t U_OD3    = U_OD2 + (size_t)NOD * 128;
static constexpr size_t U_WT1A   = U_OD3 + (size_t)NOD * 128;  // 128*256
static constexpr size_t U_WT1B   = U_WT1A + 32768;
static constexpr size_t U_WTOD2  = U_WT1B + 32768;             // 128*192
static constexpr size_t U_WTOD3  = U_WTOD2 + 24576;
static constexpr size_t U_WTDT2  = U_WTOD3 + 32768;
static constexpr size_t U_WLODT  = U_WTDT2 + 32768;            // 64*128
static constexpr size_t U_WLDTT  = U_WLODT + 8192;
static constexpr size_t U_POD    = U_WLDTT + 8192;             // 10000*64 bf16
static constexpr size_t U_PDT    = U_POD + (size_t)NOD * 64;   // 30000*64 bf16
static constexpr size_t U_SRC_DT = U_PDT + (size_t)NDT * 64;   // 30000*64 ushort
static constexpr size_t U_SRC_OD = U_SRC_DT + (size_t)NDT * CAP_DT; // 10000*96 ushort
static constexpr size_t U_END    = U_SRC_OD + (size_t)NOD * CAP_OD;
// int region (base = int* after U; memset covers both cnt arrays)
static constexpr size_t I_CNT_DT = 0;        // 30000
static constexpr size_t I_CNT_OD = 30000;    // 10000

__device__ __forceinline__ ushort_t f2bf(float f) {
    uint_t u = __float_as_uint(f);
    return (ushort_t)((u + 0x7fffu + ((u >> 16) & 1u)) >> 16);
}
__device__ __forceinline__ float bf2f(uint_t lo16) { return __uint_as_float(lo16 << 16); }

// ---------------- fused prep+fill: fill blocks FIRST (long-latency pole), then
// conv/prep_wt/fuse blocks backfill idle CUs. All parts independent.
static constexpr int NB_FILL = (NE1 / 4 + 255) / 256;                     // 489
static constexpr int NB_CONV = ((NDT * 128 + NOD * 64) / 4 + 255) / 256;  // 4375
static constexpr int NB_WT   = (155648 + 255) / 256;                      // 608
static constexpr int NB_FUSE = (16448 + 255) / 256;                       // 65
static constexpr int NB_PF   = NB_FILL + NB_CONV + NB_WT + NB_FUSE;

struct PFArgs {
    // fill
    const int *r1, *c1, *rev_src, *rev_dst;
    int *cnt_dt, *cnt_od;
    ushort_t *srcs_dt, *srcs_od;
    // conv
    const float *x_dt, *x_od;
    ushort_t *xdt_bf, *xod_bf;
    // prep_wt
    const float *od1_wl, *od1_wr, *dt1_wl, *dt1_wr;
    const float *od2_wl, *od2_wr, *od3_wl, *od3_wr, *dt2_wl, *dt2_wr;
    ushort_t *wt1a, *wt1b, *wtod2, *wtod3, *wtdt2;
    // fuse_dec
    const float *od_lw, *od_lb, *dt_lw, *dt_lb, *w1, *b1;
    ushort_t *wodt, *wdtt;
    float *bfuse;
};

__global__ __launch_bounds__(256) void prep_fill(PFArgs p) {
    int blk = blockIdx.x;
    int tid = threadIdx.x;
    if (blk < NB_FILL) {
        // ---- bucket fill (measured floor ~46us; latency/write-sector bound) ----
        int b = (blk * 256 + tid) * 4;
        if (b + 3 < NE1) {
            int4 d = *(const int4*)(p.c1 + b);
            int4 s = *(const int4*)(p.r1 + b);
            int p0 = atomicAdd(&p.cnt_dt[d.x], 1);
            int p1 = atomicAdd(&p.cnt_dt[d.y], 1);
            int p2 = atomicAdd(&p.cnt_dt[d.z], 1);
            int p3 = atomicAdd(&p.cnt_dt[d.w], 1);
            if (p0 < CAP_DT) p.srcs_dt[d.x * CAP_DT + p0] = (ushort_t)s.x;
            if (p1 < CAP_DT) p.srcs_dt[d.y * CAP_DT + p1] = (ushort_t)s.y;
            if (p2 < CAP_DT) p.srcs_dt[d.z * CAP_DT + p2] = (ushort_t)s.z;
            if (p3 < CAP_DT) p.srcs_dt[d.w * CAP_DT + p3] = (ushort_t)s.w;
        } else {
            for (int i = b; i < NE1; i++) {
                int q = atomicAdd(&p.cnt_dt[p.c1[i]], 1);
                if (q < CAP_DT) p.srcs_dt[p.c1[i] * CAP_DT + q] = (ushort_t)p.r1[i];
            }
        }
        if (b + 3 < NE2) {
            int4 d = *(const int4*)(p.rev_dst + b);
            int4 s = *(const int4*)(p.rev_src + b);
            int p0 = atomicAdd(&p.cnt_od[d.x], 1);
            int p1 = atomicAdd(&p.cnt_od[d.y], 1);
            int p2 = atomicAdd(&p.cnt_od[d.z], 1);
            int p3 = atomicAdd(&p.cnt_od[d.w], 1);
            if (p0 < CAP_OD) p.srcs_od[d.x * CAP_OD + p0] = (ushort_t)s.x;
            if (p1 < CAP_OD) p.srcs_od[d.y * CAP_OD + p1] = (ushort_t)s.y;
            if (p2 < CAP_OD) p.srcs_od[d.z * CAP_OD + p2] = (ushort_t)s.z;
            if (p3 < CAP_OD) p.srcs_od[d.w * CAP_OD + p3] = (ushort_t)s.w;
        } else if (b < NE2) {
            for (int i = b; i < NE2; i++) {
                int q = atomicAdd(&p.cnt_od[p.rev_dst[i]], 1);
                if (q < CAP_OD) p.srcs_od[p.rev_dst[i] * CAP_OD + q] = (ushort_t)p.rev_src[i];
            }
        }
        return;
    }
    blk -= NB_FILL;
    if (blk < NB_CONV) {
        // ---- x tables -> bf16 ----
        size_t i4 = ((size_t)blk * 256 + tid) * 4;
        const size_t n_dt = (size_t)NDT * 128, n_od = (size_t)NOD * 64;
        if (i4 < n_dt) {
            float4 v = *(const float4*)(p.x_dt + i4);
            ushort4 o = { f2bf(v.x), f2bf(v.y), f2bf(v.z), f2bf(v.w) };
            *(ushort4*)(p.xdt_bf + i4) = o;
        } else if (i4 - n_dt < n_od) {
            size_t j = i4 - n_dt;
            float4 v = *(const float4*)(p.x_od + j);
            ushort4 o = { f2bf(v.x), f2bf(v.y), f2bf(v.z), f2bf(v.w) };
            *(ushort4*)(p.xod_bf + j) = o;
        }
        return;
    }
    blk -= NB_CONV;
    if (blk < NB_WT) {
        // ---- combined transposed bf16 weights Wt[n][k] ----
        int i = blk * 256 + tid;
        const float* wl; const float* wr; ushort_t* dst; int q, KT;
        if (i < 32768)       { q = i;          KT = 256; wl = p.od1_wl; wr = p.od1_wr; dst = p.wt1a; }
        else if (i < 65536)  { q = i - 32768;  KT = 256; wl = p.dt1_wl; wr = p.dt1_wr; dst = p.wt1b; }
        else if (i < 90112)  { q = i - 65536;  KT = 192; wl = p.od2_wl; wr = p.od2_wr; dst = p.wtod2; }
        else if (i < 122880) { q = i - 90112;  KT = 256; wl = p.od3_wl; wr = p.od3_wr; dst = p.wtod3; }
        else if (i < 155648) { q = i - 122880; KT = 256; wl = p.dt2_wl; wr = p.dt2_wr; dst = p.wtdt2; }
        else return;
        int n = q / KT, k = q - n * KT;
        float v = (k < 128) ? wl[(size_t)k * 128 + n] : wr[(size_t)(k - 128) * 128 + n];
        dst[q] = f2bf(v);
        return;
    }
    blk -= NB_WT;
    {
        // ---- decoder weight fusion ----
        int i = blk * 256 + tid;
        if (i < 8192) {
            int r = i >> 6, q = i & 63;
            float s = 0.f;
            for (int j = 0; j < 64; j++) s = fmaf(p.od_lw[r * 64 + j], p.w1[j * 64 + q], s);
            p.wodt[q * 128 + r] = f2bf(s);
        } else if (i < 16384) {
            int w = i - 8192, r = w >> 6, q = w & 63;
            float s = 0.f;
            for (int j = 0; j < 64; j++) s = fmaf(p.dt_lw[r * 64 + j], p.w1[(64 + j) * 64 + q], s);
            p.wdtt[q * 128 + r] = f2bf(s);
        } else if (i < 16448) {
            int q = i - 16384;
            float s = p.b1[q];
            for (int j = 0; j < 64; j++) {
                s = fmaf(p.od_lb[j], p.w1[j * 64 + q], s);
                s = fmaf(p.dt_lb[j], p.w1[(64 + j) * 64 + q], s);
            }
            p.bfuse[q] = s;
        }
    }
}

// ---------------- segment mean over bf16 rows (128 cols), bf16 out ----------------
// one node per 64-thread block (measured best: R7/R10 post-mortems); ILP-8 gather.
__global__ __launch_bounds__(64) void seg_mean_bf(const ushort_t* __restrict__ X,
                                                  const int* __restrict__ cnt,
                                                  const ushort_t* __restrict__ srcs, int cap,
                                                  ushort_t* __restrict__ out) {
    int b = blockIdx.x;
    int t = threadIdx.x;             // 64 lanes, each owns cols 2t, 2t+1
    int deg = cnt[b];
    int n = deg < cap ? deg : cap;
    int start = b * cap;
    float lo[8] = {}, hi[8] = {};
    int j = 0;
    for (; j + 7 < n; j += 8) {
        uint_t v[8];
#pragma unroll
        for (int u = 0; u < 8; u++) {
            int s = srcs[start + j + u];
            v[u] = *(const uint_t*)&X[(size_t)s * 128 + 2 * t];
        }
#pragma unroll
        for (int u = 0; u < 8; u++) {
            lo[u] += bf2f(v[u] & 0xffff);
            hi[u] += __uint_as_float(v[u] & 0xffff0000u);
        }
    }
    for (; j < n; j++) {
        uint_t v = *(const uint_t*)&X[(size_t)srcs[start + j] * 128 + 2 * t];
        lo[0] += bf2f(v & 0xffff);
        hi[0] += __uint_as_float(v & 0xffff0000u);
    }
    float inv = deg > 0 ? 1.f / (float)deg : 0.f;
    float s0 = (((lo[0] + lo[1]) + (lo[2] + lo[3])) + ((lo[4] + lo[5]) + (lo[6] + lo[7]))) * inv;
    float s1 = (((hi[0] + hi[1]) + (hi[2] + hi[3])) + ((hi[4] + hi[5]) + (hi[6] + hi[7]))) * inv;
    *(uint_t*)&out[(size_t)b * 128 + 2 * t] = (uint_t)f2bf(s0) | ((uint_t)f2bf(s1) << 16);
}

// ---------------- MFMA sage layer ----------------
template <bool DUAL>
__global__ __launch_bounds__(256) void sage_mfma(
    const ushort_t* __restrict__ A1, int K1,
    const ushort_t* __restrict__ A2, int K2,
    const ushort_t* __restrict__ Wta, const ushort_t* __restrict__ Wtb,
    const float* __restrict__ ba, const float* __restrict__ bb,
    ushort_t* __restrict__ outa, ushort_t* __restrict__ outb, int M) {
    __shared__ __align__(16) ushort_t As[32 * 264];
    __shared__ __align__(16) ushort_t Wsa[128 * 40];
    __shared__ __align__(16) ushort_t Wsb[DUAL ? 128 * 40 : 8];
    const int KT = K1 + K2;
    const int AST = KT + 8;
    int t = threadIdx.x;
    int lane = t & 63, wave = t >> 6;
    int quad = lane >> 4, l16 = lane & 15;
    int mtile = wave & 1, nquad = wave >> 1;
    int mb = blockIdx.x * 32;

    int c1n = 32 * (K1 >> 3);
    for (int c = t; c < c1n; c += 256) {
        int row = c / (K1 >> 3), k8 = (c % (K1 >> 3)) * 8;
        int m = mb + row; if (m >= M) m = M - 1;
        *(short8*)&As[row * AST + k8] = *(const short8*)&A1[(size_t)m * K1 + k8];
    }
    int c2n = 32 * (K2 >> 3);
    for (int c = t; c < c2n; c += 256) {
        int row = c / (K2 >> 3), k8 = (c % (K2 >> 3)) * 8;
        int m = mb + row; if (m >= M) m = M - 1;
        *(short8*)&As[row * AST + K1 + k8] = *(const short8*)&A2[(size_t)m * K2 + k8];
    }

    f32x4 acca[4] = {};
    f32x4 accb[4] = {};
    for (int kc = 0; kc < KT; kc += 32) {
        __syncthreads();
        for (int c = t; c < 512; c += 256) {
            int n = c >> 2, k8 = (c & 3) * 8;
            *(short8*)&Wsa[n * 40 + k8] = *(const short8*)&Wta[(size_t)n * KT + kc + k8];
            if (DUAL)
                *(short8*)&Wsb[n * 40 + k8] = *(const short8*)&Wtb[(size_t)n * KT + kc + k8];
        }
        __syncthreads();
        short8 af = *(const short8*)&As[(mtile * 16 + l16) * AST + kc + quad * 8];
#pragma unroll
        for (int nt = 0; nt < 4; nt++) {
            int n = (nquad * 4 + nt) * 16 + l16;
            short8 bfr = *(const short8*)&Wsa[n * 40 + quad * 8];
            acca[nt] = __builtin_amdgcn_mfma_f32_16x16x32_bf16(af, bfr, acca[nt], 0, 0, 0);
            if (DUAL) {
                short8 bfr2 = *(const short8*)&Wsb[n * 40 + quad * 8];
                accb[nt] = __builtin_amdgcn_mfma_f32_16x16x32_bf16(af, bfr2, accb[nt], 0, 0, 0);
            }
        }
    }
    int mrow = mb + mtile * 16 + quad * 4;
#pragma unroll
    for (int nt = 0; nt < 4; nt++) {
        int n = (nquad * 4 + nt) * 16 + l16;
        float bva = ba[n];
        float bvb = DUAL ? bb[n] : 0.f;
#pragma unroll
        for (int r = 0; r < 4; r++) {
            int m = mrow + r;
            if (m < M) {
                outa[(size_t)m * 128 + n] = f2bf(fmaxf(acca[nt][r] + bva, 0.f));
                if (DUAL) outb[(size_t)m * 128 + n] = f2bf(fmaxf(accb[nt][r] + bvb, 0.f));
            }
        }
    }
}

// ---------------- MFMA linear: out[M][64] bf16 = A[M][128] bf16 @ Wt[64][128] ----------------
__global__ __launch_bounds__(256) void lin_mfma(const ushort_t* __restrict__ A,
                                                const ushort_t* __restrict__ Wt,
                                                ushort_t* __restrict__ out, int M) {
    __shared__ __align__(16) ushort_t As[64 * 136];
    __shared__ __align__(16) ushort_t Ws[64 * 40];
    int t = threadIdx.x;
    int lane = t & 63, wave = t >> 6;
    int quad = lane >> 4, l16 = lane & 15;
    int mb = blockIdx.x * 64;
    for (int c = t; c < 1024; c += 256) {
        int row = c >> 4, k8 = (c & 15) * 8;
        int m = mb + row; if (m >= M) m = M - 1;
        *(short8*)&As[row * 136 + k8] = *(const short8*)&A[(size_t)m * 128 + k8];
    }
    f32x4 acc[4] = {};
    for (int kc = 0; kc < 128; kc += 32) {
        __syncthreads();
        for (int c = t; c < 256; c += 256) {
            int n = c >> 2, k8 = (c & 3) * 8;
            *(short8*)&Ws[n * 40 + k8] = *(const short8*)&Wt[(size_t)n * 128 + kc + k8];
        }
        __syncthreads();
        short8 af = *(const short8*)&As[(wave * 16 + l16) * 136 + kc + quad * 8];
#pragma unroll
        for (int nt = 0; nt < 4; nt++) {
            short8 bfr = *(const short8*)&Ws[(nt * 16 + l16) * 40 + quad * 8];
            acc[nt] = __builtin_amdgcn_mfma_f32_16x16x32_bf16(af, bfr, acc[nt], 0, 0, 0);
        }
    }
    int mrow = mb + wave * 16 + quad * 4;
#pragma unroll
    for (int nt = 0; nt < 4; nt++) {
        int n = nt * 16 + l16;
#pragma unroll
        for (int r = 0; r < 4; r++) {
            int m = mrow + r;
            if (m < M) out[(size_t)m * 64 + n] = f2bf(acc[nt][r]);
        }
    }
}

// ---------------- decoder: bf16 P gathers, f32 output ----------------
__global__ __launch_bounds__(256) void decode(const ushort_t* __restrict__ P_od, const ushort_t* __restrict__ P_dt,
                                              const int* __restrict__ el_src, const int* __restrict__ el_dst,
                                              const float* __restrict__ bfuse, const float* __restrict__ w2,
                                              const float* __restrict__ b2v, float* __restrict__ out) {
    __shared__ __align__(16) float bf[64];
    __shared__ __align__(16) float w2s[64];
    int t = threadIdx.x;
    if (t < 64) { bf[t] = bfuse[t]; w2s[t] = w2[t]; }
    __syncthreads();
    int e = blockIdx.x * 256 + t;
    if (e >= NEL) return;
    const uint4* po = (const uint4*)(P_od + (size_t)el_src[e] * 64);
    const uint4* pt = (const uint4*)(P_dt + (size_t)el_dst[e] * 64);
    float acc = 0.f;
#pragma unroll
    for (int c = 0; c < 8; c++) {
        uint4 a = po[c], b = pt[c];
        const uint_t* au = (const uint_t*)&a;
        const uint_t* bu = (const uint_t*)&b;
#pragma unroll
        for (int j = 0; j < 4; j++) {
            int idx = c * 8 + j * 2;
            float lo = bf2f(au[j] & 0xffff) + bf2f(bu[j] & 0xffff) + bf[idx];
            float hi = __uint_as_float(au[j] & 0xffff0000u) + __uint_as_float(bu[j] & 0xffff0000u) + bf[idx + 1];
            acc = fmaf(fmaxf(lo, 0.f), w2s[idx], acc);
            acc = fmaf(fmaxf(hi, 0.f), w2s[idx + 1], acc);
        }
    }
    float z = acc + b2v[0];
    out[e] = 1.f / (1.f + __expf(-z));
}

// ---------------- launch ----------------
extern "C" void kernel_launch(void* const* d_in, const int* in_sizes, int n_in,
                              void* d_out, int out_size, void* d_ws, size_t ws_size,
                              hipStream_t stream) {
    float* W = (float*)d_ws;
    ushort_t* U = (ushort_t*)(W + F_ENDF);
    int* I = (int*)(U + U_END);

    const float* x_dt   = (const float*)d_in[0];
    const float* x_od   = (const float*)d_in[1];
    const int* ei       = (const int*)d_in[2];
    const int* r1 = ei;
    const int* c1 = ei + NE1;
    const int* rev_src  = (const int*)d_in[3];
    const int* rev_dst  = (const int*)d_in[4];
    const int* el_src   = (const int*)d_in[5];
    const int* el_dst   = (const int*)d_in[6];
    const float* od1_wl = (const float*)d_in[7],  *od1_wr = (const float*)d_in[8],  *od1_b = (const float*)d_in[9];
    const float* od2_wl = (const float*)d_in[10], *od2_wr = (const float*)d_in[11], *od2_b = (const float*)d_in[12];
    const float* od3_wl = (const float*)d_in[13], *od3_wr = (const float*)d_in[14], *od3_b = (const float*)d_in[15];
    const float* od_lw  = (const float*)d_in[16], *od_lb  = (const float*)d_in[17];
    const float* dt1_wl = (const float*)d_in[18], *dt1_wr = (const float*)d_in[19], *dt1_b = (const float*)d_in[20];
    const float* dt2_wl = (const float*)d_in[21], *dt2_wr = (const float*)d_in[22], *dt2_b = (const float*)d_in[23];
    const float* dt_lw  = (const float*)d_in[24], *dt_lb  = (const float*)d_in[25];
    const float* dec_w1 = (const float*)d_in[26], *dec_b1 = (const float*)d_in[27];
    const float* dec_w2 = (const float*)d_in[28], *dec_b2 = (const float*)d_in[29];

    hipMemsetAsync(I + I_CNT_DT, 0, (NDT + NOD) * sizeof(int), stream);

    PFArgs p;
    p.r1 = r1; p.c1 = c1; p.rev_src = rev_src; p.rev_dst = rev_dst;
    p.cnt_dt = I + I_CNT_DT; p.cnt_od = I + I_CNT_OD;
    p.srcs_dt = U + U_SRC_DT; p.srcs_od = U + U_SRC_OD;
    p.x_dt = x_dt; p.x_od = x_od;
    p.xdt_bf = U + U_XDT; p.xod_bf = U + U_XOD;
    p.od1_wl = od1_wl; p.od1_wr = od1_wr; p.dt1_wl = dt1_wl; p.dt1_wr = dt1_wr;
    p.od2_wl = od2_wl; p.od2_wr = od2_wr; p.od3_wl = od3_wl; p.od3_wr = od3_wr;
    p.dt2_wl = dt2_wl; p.dt2_wr = dt2_wr;
    p.wt1a = U + U_WT1A; p.wt1b = U + U_WT1B; p.wtod2 = U + U_WTOD2;
    p.wtod3 = U + U_WTOD3; p.wtdt2 = U + U_WTDT2;
    p.od_lw = od_lw; p.od_lb = od_lb; p.dt_lw = dt_lw; p.dt_lb = dt_lb;
    p.w1 = dec_w1; p.b1 = dec_b1;
    p.wodt = U + U_WLODT; p.wdtt = U + U_WLDTT;
    p.bfuse = W + F_BFUSE;
    prep_fill<<<NB_PF, 256, 0, stream>>>(p);

    // agg_x = segmean(x_dt)
    seg_mean_bf<<<NDT, 64, 0, stream>>>(U + U_XDT, I + I_CNT_DT, U + U_SRC_DT, CAP_DT, U + U_AGGX);
    // h, d1 (dual MFMA)
    sage_mfma<true><<<(NDT + 31) / 32, 256, 0, stream>>>(U + U_AGGX, 128, U + U_XDT, 128,
                                                         U + U_WT1A, U + U_WT1B, od1_b, dt1_b,
                                                         U + U_H, U + U_D1, NDT);
    // agg_h = segmean(h) over rev graph
    seg_mean_bf<<<NOD, 64, 0, stream>>>(U + U_H, I + I_CNT_OD, U + U_SRC_OD, CAP_OD, U + U_AGGH);
    // od2
    sage_mfma<false><<<(NOD + 31) / 32, 256, 0, stream>>>(U + U_AGGH, 128, U + U_XOD, 64,
                                                          U + U_WTOD2, nullptr, od2_b, nullptr,
                                                          U + U_OD2, nullptr, NOD);
    // od3
    sage_mfma<false><<<(NOD + 31) / 32, 256, 0, stream>>>(U + U_AGGH, 128, U + U_OD2, 128,
                                                          U + U_WTOD3, nullptr, od3_b, nullptr,
                                                          U + U_OD3, nullptr, NOD);
    // agg_d = segmean(d1)
    seg_mean_bf<<<NDT, 64, 0, stream>>>(U + U_D1, I + I_CNT_DT, U + U_SRC_DT, CAP_DT, U + U_AGGX);
    // d2
    sage_mfma<false><<<(NDT + 31) / 32, 256, 0, stream>>>(U + U_AGGX, 128, U + U_D1, 128,
                                                          U + U_WTDT2, nullptr, dt2_b, nullptr,
                                                          U + U_H, nullptr, NDT);
    // P tables (bf16)
    lin_mfma<<<(NOD + 63) / 64, 256, 0, stream>>>(U + U_OD3, U + U_WLODT, U + U_POD, NOD);
    lin_mfma<<<(NDT + 63) / 64, 256, 0, stream>>>(U + U_H, U + U_WLDTT, U + U_PDT, NDT);
    // decoder
    decode<<<(NEL + 255) / 256, 256, 0, stream>>>(U + U_POD, U + U_PDT, el_src, el_dst,
                                                  W + F_BFUSE, dec_w2, dec_b2, (float*)d_out);
}

// Round 13
// 278.184 us; speedup vs baseline: 1.1410x; 1.0615x over previous
//
#include <hip/hip_runtime.h>
#include <hip/hip_bf16.h>

#define NDT 30000
#define NOD 10000
#define NE1 500000
#define NE2 300000
#define NEL 200000
#define CAP_DT 64
#define CAP_OD 96

typedef unsigned short ushort_t;
typedef unsigned int uint_t;
typedef __attribute__((ext_vector_type(8))) short short8;
typedef __attribute__((ext_vector_type(4))) float f32x4;

// ---------------- workspace layout ----------------
static constexpr size_t F_BFUSE = 0;                          // 64
static constexpr size_t F_ENDF  = 64;
static constexpr size_t U_XDT    = 0;
static constexpr size_t U_XOD    = U_XDT + (size_t)NDT * 128;
static constexpr size_t U_AGGX   = U_XOD + (size_t)NOD * 64;   // agg_x, later agg_d
static constexpr size_t U_H      = U_AGGX + (size_t)NDT * 128; // h, later d2
static constexpr size_t U_D1     = U_H + (size_t)NDT * 128;
static constexpr size_t U_AGGH   = U_D1 + (size_t)NDT * 128;
static constexpr size_t U_OD2    = U_AGGH + (size_t)NOD * 128;
static constexpr size_t U_OD3    = U_OD2 + (size_t)NOD * 128;
static constexpr size_t U_WT1A   = U_OD3 + (size_t)NOD * 128;
static constexpr size_t U_WT1B   = U_WT1A + 32768;
static constexpr size_t U_WTOD2  = U_WT1B + 32768;
static constexpr size_t U_WTOD3  = U_WTOD2 + 24576;
static constexpr size_t U_WTDT2  = U_WTOD3 + 32768;
static constexpr size_t U_WLODT  = U_WTDT2 + 32768;
static constexpr size_t U_WLDTT  = U_WLODT + 8192;
static constexpr size_t U_POD    = U_WLDTT + 8192;
static constexpr size_t U_PDT    = U_POD + (size_t)NOD * 64;
static constexpr size_t U_SRC_DT = U_PDT + (size_t)NDT * 64;
static constexpr size_t U_SRC_OD = U_SRC_DT + (size_t)NDT * CAP_DT;
static constexpr size_t U_END    = U_SRC_OD + (size_t)NOD * CAP_OD;
static constexpr size_t I_CNT_DT = 0;
static constexpr size_t I_CNT_OD = 30000;

__device__ __forceinline__ ushort_t f2bf(float f) {
    uint_t u = __float_as_uint(f);
    return (ushort_t)((u + 0x7fffu + ((u >> 16) & 1u)) >> 16);
}
__device__ __forceinline__ float bf2f(uint_t lo16) { return __uint_as_float(lo16 << 16); }

// ---------------- fused prep+fill (fill first = long pole; R12 win) ----------------
static constexpr int NB_FILL = (NE1 / 4 + 255) / 256;
static constexpr int NB_CONV = ((NDT * 128 + NOD * 64) / 4 + 255) / 256;
static constexpr int NB_WT   = (155648 + 255) / 256;
static constexpr int NB_FUSE = (16448 + 255) / 256;
static constexpr int NB_PF   = NB_FILL + NB_CONV + NB_WT + NB_FUSE;

struct PFArgs {
    const int *r1, *c1, *rev_src, *rev_dst;
    int *cnt_dt, *cnt_od;
    ushort_t *srcs_dt, *srcs_od;
    const float *x_dt, *x_od;
    ushort_t *xdt_bf, *xod_bf;
    const float *od1_wl, *od1_wr, *dt1_wl, *dt1_wr;
    const float *od2_wl, *od2_wr, *od3_wl, *od3_wr, *dt2_wl, *dt2_wr;
    ushort_t *wt1a, *wt1b, *wtod2, *wtod3, *wtdt2;
    const float *od_lw, *od_lb, *dt_lw, *dt_lb, *w1, *b1;
    ushort_t *wodt, *wdtt;
    float *bfuse;
};

__global__ __launch_bounds__(256) void prep_fill(PFArgs p) {
    int blk = blockIdx.x;
    int tid = threadIdx.x;
    if (blk < NB_FILL) {
        int b = (blk * 256 + tid) * 4;
        if (b + 3 < NE1) {
            int4 d = *(const int4*)(p.c1 + b);
            int4 s = *(const int4*)(p.r1 + b);
            int p0 = atomicAdd(&p.cnt_dt[d.x], 1);
            int p1 = atomicAdd(&p.cnt_dt[d.y], 1);
            int p2 = atomicAdd(&p.cnt_dt[d.z], 1);
            int p3 = atomicAdd(&p.cnt_dt[d.w], 1);
            if (p0 < CAP_DT) p.srcs_dt[d.x * CAP_DT + p0] = (ushort_t)s.x;
            if (p1 < CAP_DT) p.srcs_dt[d.y * CAP_DT + p1] = (ushort_t)s.y;
            if (p2 < CAP_DT) p.srcs_dt[d.z * CAP_DT + p2] = (ushort_t)s.z;
            if (p3 < CAP_DT) p.srcs_dt[d.w * CAP_DT + p3] = (ushort_t)s.w;
        } else {
            for (int i = b; i < NE1; i++) {
                int q = atomicAdd(&p.cnt_dt[p.c1[i]], 1);
                if (q < CAP_DT) p.srcs_dt[p.c1[i] * CAP_DT + q] = (ushort_t)p.r1[i];
            }
        }
        if (b + 3 < NE2) {
            int4 d = *(const int4*)(p.rev_dst + b);
            int4 s = *(const int4*)(p.rev_src + b);
            int p0 = atomicAdd(&p.cnt_od[d.x], 1);
            int p1 = atomicAdd(&p.cnt_od[d.y], 1);
            int p2 = atomicAdd(&p.cnt_od[d.z], 1);
            int p3 = atomicAdd(&p.cnt_od[d.w], 1);
            if (p0 < CAP_OD) p.srcs_od[d.x * CAP_OD + p0] = (ushort_t)s.x;
            if (p1 < CAP_OD) p.srcs_od[d.y * CAP_OD + p1] = (ushort_t)s.y;
            if (p2 < CAP_OD) p.srcs_od[d.z * CAP_OD + p2] = (ushort_t)s.z;
            if (p3 < CAP_OD) p.srcs_od[d.w * CAP_OD + p3] = (ushort_t)s.w;
        } else if (b < NE2) {
            for (int i = b; i < NE2; i++) {
                int q = atomicAdd(&p.cnt_od[p.rev_dst[i]], 1);
                if (q < CAP_OD) p.srcs_od[p.rev_dst[i] * CAP_OD + q] = (ushort_t)p.rev_src[i];
            }
        }
        return;
    }
    blk -= NB_FILL;
    if (blk < NB_CONV) {
        size_t i4 = ((size_t)blk * 256 + tid) * 4;
        const size_t n_dt = (size_t)NDT * 128, n_od = (size_t)NOD * 64;
        if (i4 < n_dt) {
            float4 v = *(const float4*)(p.x_dt + i4);
            ushort4 o = { f2bf(v.x), f2bf(v.y), f2bf(v.z), f2bf(v.w) };
            *(ushort4*)(p.xdt_bf + i4) = o;
        } else if (i4 - n_dt < n_od) {
            size_t j = i4 - n_dt;
            float4 v = *(const float4*)(p.x_od + j);
            ushort4 o = { f2bf(v.x), f2bf(v.y), f2bf(v.z), f2bf(v.w) };
            *(ushort4*)(p.xod_bf + j) = o;
        }
        return;
    }
    blk -= NB_CONV;
    if (blk < NB_WT) {
        int i = blk * 256 + tid;
        const float* wl; const float* wr; ushort_t* dst; int q, KT;
        if (i < 32768)       { q = i;          KT = 256; wl = p.od1_wl; wr = p.od1_wr; dst = p.wt1a; }
        else if (i < 65536)  { q = i - 32768;  KT = 256; wl = p.dt1_wl; wr = p.dt1_wr; dst = p.wt1b; }
        else if (i < 90112)  { q = i - 65536;  KT = 192; wl = p.od2_wl; wr = p.od2_wr; dst = p.wtod2; }
        else if (i < 122880) { q = i - 90112;  KT = 256; wl = p.od3_wl; wr = p.od3_wr; dst = p.wtod3; }
        else if (i < 155648) { q = i - 122880; KT = 256; wl = p.dt2_wl; wr = p.dt2_wr; dst = p.wtdt2; }
        else return;
        int n = q / KT, k = q - n * KT;
        float v = (k < 128) ? wl[(size_t)k * 128 + n] : wr[(size_t)(k - 128) * 128 + n];
        dst[q] = f2bf(v);
        return;
    }
    blk -= NB_WT;
    {
        int i = blk * 256 + tid;
        if (i < 8192) {
            int r = i >> 6, q = i & 63;
            float s = 0.f;
            for (int j = 0; j < 64; j++) s = fmaf(p.od_lw[r * 64 + j], p.w1[j * 64 + q], s);
            p.wodt[q * 128 + r] = f2bf(s);
        } else if (i < 16384) {
            int w = i - 8192, r = w >> 6, q = w & 63;
            float s = 0.f;
            for (int j = 0; j < 64; j++) s = fmaf(p.dt_lw[r * 64 + j], p.w1[(64 + j) * 64 + q], s);
            p.wdtt[q * 128 + r] = f2bf(s);
        } else if (i < 16448) {
            int q = i - 16384;
            float s = p.b1[q];
            for (int j = 0; j < 64; j++) {
                s = fmaf(p.od_lb[j], p.w1[j * 64 + q], s);
                s = fmaf(p.dt_lb[j], p.w1[(64 + j) * 64 + q], s);
            }
            p.bfuse[q] = s;
        }
    }
}

// ---------------- segment mean body (ILP-8 gather; one node per 64t block) ----------------
__device__ __forceinline__ void seg_mean_body(const ushort_t* __restrict__ X,
                                              const int* __restrict__ cnt,
                                              const ushort_t* __restrict__ srcs, int cap,
                                              ushort_t* __restrict__ out, int b, int t) {
    int deg = cnt[b];
    int n = deg < cap ? deg : cap;
    int start = b * cap;
    float lo[8] = {}, hi[8] = {};
    int j = 0;
    for (; j + 7 < n; j += 8) {
        uint_t v[8];
#pragma unroll
        for (int u = 0; u < 8; u++) {
            int s = srcs[start + j + u];
            v[u] = *(const uint_t*)&X[(size_t)s * 128 + 2 * t];
        }
#pragma unroll
        for (int u = 0; u < 8; u++) {
            lo[u] += bf2f(v[u] & 0xffff);
            hi[u] += __uint_as_float(v[u] & 0xffff0000u);
        }
    }
    for (; j < n; j++) {
        uint_t v = *(const uint_t*)&X[(size_t)srcs[start + j] * 128 + 2 * t];
        lo[0] += bf2f(v & 0xffff);
        hi[0] += __uint_as_float(v & 0xffff0000u);
    }
    float inv = deg > 0 ? 1.f / (float)deg : 0.f;
    float s0 = (((lo[0] + lo[1]) + (lo[2] + lo[3])) + ((lo[4] + lo[5]) + (lo[6] + lo[7]))) * inv;
    float s1 = (((hi[0] + hi[1]) + (hi[2] + hi[3])) + ((hi[4] + hi[5]) + (hi[6] + hi[7]))) * inv;
    *(uint_t*)&out[(size_t)b * 128 + 2 * t] = (uint_t)f2bf(s0) | ((uint_t)f2bf(s1) << 16);
}

__global__ __launch_bounds__(64) void seg_mean_bf(const ushort_t* __restrict__ X,
                                                  const int* __restrict__ cnt,
                                                  const ushort_t* __restrict__ srcs, int cap,
                                                  ushort_t* __restrict__ out) {
    seg_mean_body(X, cnt, srcs, cap, out, blockIdx.x, threadIdx.x);
}

// fused: job A (agg_d over dt graph, NDT blocks, long pole first) + job B (agg_h)
__global__ __launch_bounds__(64) void seg_mean2(const ushort_t* Xa, const int* cnta, const ushort_t* srca,
                                                int capa, ushort_t* outa, int Na,
                                                const ushort_t* Xb, const int* cntb, const ushort_t* srcb,
                                                int capb, ushort_t* outb) {
    int b = blockIdx.x;
    if (b < Na) seg_mean_body(Xa, cnta, srca, capa, outa, b, threadIdx.x);
    else        seg_mean_body(Xb, cntb, srcb, capb, outb, b - Na, threadIdx.x);
}

// ---------------- MFMA sage layer (dual-output variant for layer 1) ----------------
template <bool DUAL>
__global__ __launch_bounds__(256) void sage_mfma(
    const ushort_t* __restrict__ A1, int K1,
    const ushort_t* __restrict__ A2, int K2,
    const ushort_t* __restrict__ Wta, const ushort_t* __restrict__ Wtb,
    const float* __restrict__ ba, const float* __restrict__ bb,
    ushort_t* __restrict__ outa, ushort_t* __restrict__ outb, int M) {
    __shared__ __align__(16) ushort_t As[32 * 264];
    __shared__ __align__(16) ushort_t Wsa[128 * 40];
    __shared__ __align__(16) ushort_t Wsb[DUAL ? 128 * 40 : 8];
    const int KT = K1 + K2;
    const int AST = KT + 8;
    int t = threadIdx.x;
    int lane = t & 63, wave = t >> 6;
    int quad = lane >> 4, l16 = lane & 15;
    int mtile = wave & 1, nquad = wave >> 1;
    int mb = blockIdx.x * 32;

    int c1n = 32 * (K1 >> 3);
    for (int c = t; c < c1n; c += 256) {
        int row = c / (K1 >> 3), k8 = (c % (K1 >> 3)) * 8;
        int m = mb + row; if (m >= M) m = M - 1;
        *(short8*)&As[row * AST + k8] = *(const short8*)&A1[(size_t)m * K1 + k8];
    }
    int c2n = 32 * (K2 >> 3);
    for (int c = t; c < c2n; c += 256) {
        int row = c / (K2 >> 3), k8 = (c % (K2 >> 3)) * 8;
        int m = mb + row; if (m >= M) m = M - 1;
        *(short8*)&As[row * AST + K1 + k8] = *(const short8*)&A2[(size_t)m * K2 + k8];
    }
    f32x4 acca[4] = {};
    f32x4 accb[4] = {};
    for (int kc = 0; kc < KT; kc += 32) {
        __syncthreads();
        for (int c = t; c < 512; c += 256) {
            int n = c >> 2, k8 = (c & 3) * 8;
            *(short8*)&Wsa[n * 40 + k8] = *(const short8*)&Wta[(size_t)n * KT + kc + k8];
            if (DUAL)
                *(short8*)&Wsb[n * 40 + k8] = *(const short8*)&Wtb[(size_t)n * KT + kc + k8];
        }
        __syncthreads();
        short8 af = *(const short8*)&As[(mtile * 16 + l16) * AST + kc + quad * 8];
#pragma unroll
        for (int nt = 0; nt < 4; nt++) {
            int n = (nquad * 4 + nt) * 16 + l16;
            short8 bfr = *(const short8*)&Wsa[n * 40 + quad * 8];
            acca[nt] = __builtin_amdgcn_mfma_f32_16x16x32_bf16(af, bfr, acca[nt], 0, 0, 0);
            if (DUAL) {
                short8 bfr2 = *(const short8*)&Wsb[n * 40 + quad * 8];
                accb[nt] = __builtin_amdgcn_mfma_f32_16x16x32_bf16(af, bfr2, accb[nt], 0, 0, 0);
            }
        }
    }
    int mrow = mb + mtile * 16 + quad * 4;
#pragma unroll
    for (int nt = 0; nt < 4; nt++) {
        int n = (nquad * 4 + nt) * 16 + l16;
        float bva = ba[n];
        float bvb = DUAL ? bb[n] : 0.f;
#pragma unroll
        for (int r = 0; r < 4; r++) {
            int m = mrow + r;
            if (m < M) {
                outa[(size_t)m * 128 + n] = f2bf(fmaxf(acca[nt][r] + bva, 0.f));
                if (DUAL) outb[(size_t)m * 128 + n] = f2bf(fmaxf(accb[nt][r] + bvb, 0.f));
            }
        }
    }
}

// ---------------- fused two-job single-output sage ----------------
struct SageJob {
    const ushort_t *A1, *A2;
    int K1, K2;
    const ushort_t *Wt;
    const float *bias;
    ushort_t *out;
    int M;
};

__global__ __launch_bounds__(256) void sage_two(SageJob ja, int nb_a, SageJob jb) {
    __shared__ __align__(16) ushort_t As[32 * 264];
    __shared__ __align__(16) ushort_t Wsa[128 * 40];
    SageJob j;
    int blk;
    if (blockIdx.x < nb_a) { j = ja; blk = blockIdx.x; }
    else                   { j = jb; blk = blockIdx.x - nb_a; }
    const int KT = j.K1 + j.K2;
    const int AST = KT + 8;
    int t = threadIdx.x;
    int lane = t & 63, wave = t >> 6;
    int quad = lane >> 4, l16 = lane & 15;
    int mtile = wave & 1, nquad = wave >> 1;
    int mb = blk * 32;

    int c1n = 32 * (j.K1 >> 3);
    for (int c = t; c < c1n; c += 256) {
        int row = c / (j.K1 >> 3), k8 = (c % (j.K1 >> 3)) * 8;
        int m = mb + row; if (m >= j.M) m = j.M - 1;
        *(short8*)&As[row * AST + k8] = *(const short8*)&j.A1[(size_t)m * j.K1 + k8];
    }
    int c2n = 32 * (j.K2 >> 3);
    for (int c = t; c < c2n; c += 256) {
        int row = c / (j.K2 >> 3), k8 = (c % (j.K2 >> 3)) * 8;
        int m = mb + row; if (m >= j.M) m = j.M - 1;
        *(short8*)&As[row * AST + j.K1 + k8] = *(const short8*)&j.A2[(size_t)m * j.K2 + k8];
    }
    f32x4 acc[4] = {};
    for (int kc = 0; kc < KT; kc += 32) {
        __syncthreads();
        for (int c = t; c < 512; c += 256) {
            int n = c >> 2, k8 = (c & 3) * 8;
            *(short8*)&Wsa[n * 40 + k8] = *(const short8*)&j.Wt[(size_t)n * KT + kc + k8];
        }
        __syncthreads();
        short8 af = *(const short8*)&As[(mtile * 16 + l16) * AST + kc + quad * 8];
#pragma unroll
        for (int nt = 0; nt < 4; nt++) {
            int n = (nquad * 4 + nt) * 16 + l16;
            short8 bfr = *(const short8*)&Wsa[n * 40 + quad * 8];
            acc[nt] = __builtin_amdgcn_mfma_f32_16x16x32_bf16(af, bfr, acc[nt], 0, 0, 0);
        }
    }
    int mrow = mb + mtile * 16 + quad * 4;
#pragma unroll
    for (int nt = 0; nt < 4; nt++) {
        int n = (nquad * 4 + nt) * 16 + l16;
        float bv = j.bias[n];
#pragma unroll
        for (int r = 0; r < 4; r++) {
            int m = mrow + r;
            if (m < j.M) j.out[(size_t)m * 128 + n] = f2bf(fmaxf(acc[nt][r] + bv, 0.f));
        }
    }
}

// ---------------- MFMA linear (two-job fused): out[M][64] bf16 ----------------
struct LinJob {
    const ushort_t *A, *Wt;
    ushort_t *out;
    int M;
};

__device__ __forceinline__ void lin_body(const LinJob& j, int blk, int t) {
    __shared__ __align__(16) ushort_t As[64 * 136];
    __shared__ __align__(16) ushort_t Ws[64 * 40];
    int lane = t & 63, wave = t >> 6;
    int quad = lane >> 4, l16 = lane & 15;
    int mb = blk * 64;
    for (int c = t; c < 1024; c += 256) {
        int row = c >> 4, k8 = (c & 15) * 8;
        int m = mb + row; if (m >= j.M) m = j.M - 1;
        *(short8*)&As[row * 136 + k8] = *(const short8*)&j.A[(size_t)m * 128 + k8];
    }
    f32x4 acc[4] = {};
    for (int kc = 0; kc < 128; kc += 32) {
        __syncthreads();
        for (int c = t; c < 256; c += 256) {
            int n = c >> 2, k8 = (c & 3) * 8;
            *(short8*)&Ws[n * 40 + k8] = *(const short8*)&j.Wt[(size_t)n * 128 + kc + k8];
        }
        __syncthreads();
        short8 af = *(const short8*)&As[(wave * 16 + l16) * 136 + kc + quad * 8];
#pragma unroll
        for (int nt = 0; nt < 4; nt++) {
            short8 bfr = *(const short8*)&Ws[(nt * 16 + l16) * 40 + quad * 8];
            acc[nt] = __builtin_amdgcn_mfma_f32_16x16x32_bf16(af, bfr, acc[nt], 0, 0, 0);
        }
    }
    int mrow = mb + wave * 16 + quad * 4;
#pragma unroll
    for (int nt = 0; nt < 4; nt++) {
        int n = nt * 16 + l16;
#pragma unroll
        for (int r = 0; r < 4; r++) {
            int m = mrow + r;
            if (m < j.M) j.out[(size_t)m * 64 + n] = f2bf(acc[nt][r]);
        }
    }
}

__global__ __launch_bounds__(256) void lin_two(LinJob ja, int nb_a, LinJob jb) {
    if (blockIdx.x < nb_a) lin_body(ja, blockIdx.x, threadIdx.x);
    else                   lin_body(jb, blockIdx.x - nb_a, threadIdx.x);
}

// ---------------- decoder: bf16 P gathers, f32 output ----------------
__global__ __launch_bounds__(256) void decode(const ushort_t* __restrict__ P_od, const ushort_t* __restrict__ P_dt,
                                              const int* __restrict__ el_src, const int* __restrict__ el_dst,
                                              const float* __restrict__ bfuse, const float* __restrict__ w2,
                                              const float* __restrict__ b2v, float* __restrict__ out) {
    __shared__ __align__(16) float bf[64];
    __shared__ __align__(16) float w2s[64];
    int t = threadIdx.x;
    if (t < 64) { bf[t] = bfuse[t]; w2s[t] = w2[t]; }
    __syncthreads();
    int e = blockIdx.x * 256 + t;
    if (e >= NEL) return;
    const uint4* po = (const uint4*)(P_od + (size_t)el_src[e] * 64);
    const uint4* pt = (const uint4*)(P_dt + (size_t)el_dst[e] * 64);
    float acc = 0.f;
#pragma unroll
    for (int c = 0; c < 8; c++) {
        uint4 a = po[c], b = pt[c];
        const uint_t* au = (const uint_t*)&a;
        const uint_t* bu = (const uint_t*)&b;
#pragma unroll
        for (int j = 0; j < 4; j++) {
            int idx = c * 8 + j * 2;
            float lo = bf2f(au[j] & 0xffff) + bf2f(bu[j] & 0xffff) + bf[idx];
            float hi = __uint_as_float(au[j] & 0xffff0000u) + __uint_as_float(bu[j] & 0xffff0000u) + bf[idx + 1];
            acc = fmaf(fmaxf(lo, 0.f), w2s[idx], acc);
            acc = fmaf(fmaxf(hi, 0.f), w2s[idx + 1], acc);
        }
    }
    float z = acc + b2v[0];
    out[e] = 1.f / (1.f + __expf(-z));
}

// ---------------- launch ----------------
extern "C" void kernel_launch(void* const* d_in, const int* in_sizes, int n_in,
                              void* d_out, int out_size, void* d_ws, size_t ws_size,
                              hipStream_t stream) {
    float* W = (float*)d_ws;
    ushort_t* U = (ushort_t*)(W + F_ENDF);
    int* I = (int*)(U + U_END);

    const float* x_dt   = (const float*)d_in[0];
    const float* x_od   = (const float*)d_in[1];
    const int* ei       = (const int*)d_in[2];
    const int* r1 = ei;
    const int* c1 = ei + NE1;
    const int* rev_src  = (const int*)d_in[3];
    const int* rev_dst  = (const int*)d_in[4];
    const int* el_src   = (const int*)d_in[5];
    const int* el_dst   = (const int*)d_in[6];
    const float* od1_wl = (const float*)d_in[7],  *od1_wr = (const float*)d_in[8],  *od1_b = (const float*)d_in[9];
    const float* od2_wl = (const float*)d_in[10], *od2_wr = (const float*)d_in[11], *od2_b = (const float*)d_in[12];
    const float* od3_wl = (const float*)d_in[13], *od3_wr = (const float*)d_in[14], *od3_b = (const float*)d_in[15];
    const float* od_lw  = (const float*)d_in[16], *od_lb  = (const float*)d_in[17];
    const float* dt1_wl = (const float*)d_in[18], *dt1_wr = (const float*)d_in[19], *dt1_b = (const float*)d_in[20];
    const float* dt2_wl = (const float*)d_in[21], *dt2_wr = (const float*)d_in[22], *dt2_b = (const float*)d_in[23];
    const float* dt_lw  = (const float*)d_in[24], *dt_lb  = (const float*)d_in[25];
    const float* dec_w1 = (const float*)d_in[26], *dec_b1 = (const float*)d_in[27];
    const float* dec_w2 = (const float*)d_in[28], *dec_b2 = (const float*)d_in[29];

    hipMemsetAsync(I + I_CNT_DT, 0, (NDT + NOD) * sizeof(int), stream);

    PFArgs p;
    p.r1 = r1; p.c1 = c1; p.rev_src = rev_src; p.rev_dst = rev_dst;
    p.cnt_dt = I + I_CNT_DT; p.cnt_od = I + I_CNT_OD;
    p.srcs_dt = U + U_SRC_DT; p.srcs_od = U + U_SRC_OD;
    p.x_dt = x_dt; p.x_od = x_od;
    p.xdt_bf = U + U_XDT; p.xod_bf = U + U_XOD;
    p.od1_wl = od1_wl; p.od1_wr = od1_wr; p.dt1_wl = dt1_wl; p.dt1_wr = dt1_wr;
    p.od2_wl = od2_wl; p.od2_wr = od2_wr; p.od3_wl = od3_wl; p.od3_wr = od3_wr;
    p.dt2_wl = dt2_wl; p.dt2_wr = dt2_wr;
    p.wt1a = U + U_WT1A; p.wt1b = U + U_WT1B; p.wtod2 = U + U_WTOD2;
    p.wtod3 = U + U_WTOD3; p.wtdt2 = U + U_WTDT2;
    p.od_lw = od_lw; p.od_lb = od_lb; p.dt_lw = dt_lw; p.dt_lb = dt_lb;
    p.w1 = dec_w1; p.b1 = dec_b1;
    p.wodt = U + U_WLODT; p.wdtt = U + U_WLDTT;
    p.bfuse = W + F_BFUSE;
    prep_fill<<<NB_PF, 256, 0, stream>>>(p);

    // agg_x = segmean(x_dt) over dt graph
    seg_mean_bf<<<NDT, 64, 0, stream>>>(U + U_XDT, I + I_CNT_DT, U + U_SRC_DT, CAP_DT, U + U_AGGX);
    // h, d1 (dual MFMA)
    sage_mfma<true><<<(NDT + 31) / 32, 256, 0, stream>>>(U + U_AGGX, 128, U + U_XDT, 128,
                                                         U + U_WT1A, U + U_WT1B, od1_b, dt1_b,
                                                         U + U_H, U + U_D1, NDT);
    // fused: agg_d = segmean(d1) [long pole first] + agg_h = segmean(h)
    seg_mean2<<<NDT + NOD, 64, 0, stream>>>(U + U_D1, I + I_CNT_DT, U + U_SRC_DT, CAP_DT, U + U_AGGX, NDT,
                                            U + U_H, I + I_CNT_OD, U + U_SRC_OD, CAP_OD, U + U_AGGH);
    // fused: d2 [938 blocks, first] + od2 [313 blocks]
    {
        SageJob jd2 = { U + U_AGGX, U + U_D1, 128, 128, U + U_WTDT2, dt2_b, U + U_H, NDT };
        SageJob jod2 = { U + U_AGGH, U + U_XOD, 128, 64, U + U_WTOD2, od2_b, U + U_OD2, NOD };
        int nb_d2 = (NDT + 31) / 32;
        int nb_od2 = (NOD + 31) / 32;
        sage_two<<<nb_d2 + nb_od2, 256, 0, stream>>>(jd2, nb_d2, jod2);
    }
    // od3 = relu(agg_h@od3_wl + od2@od3_wr + b)
    sage_mfma<false><<<(NOD + 31) / 32, 256, 0, stream>>>(U + U_AGGH, 128, U + U_OD2, 128,
                                                          U + U_WTOD3, nullptr, od3_b, nullptr,
                                                          U + U_OD3, nullptr, NOD);
    // fused P tables: lin_dt [469 blocks, first] + lin_od [157 blocks]
    {
        LinJob jdt = { U + U_H, U + U_WLDTT, U + U_PDT, NDT };
        LinJob jod = { U + U_OD3, U + U_WLODT, U + U_POD, NOD };
        int nb_dt = (NDT + 63) / 64;
        int nb_od = (NOD + 63) / 64;
        lin_two<<<nb_dt + nb_od, 256, 0, stream>>>(jdt, nb_dt, jod);
    }
    // decoder
    decode<<<(NEL + 255) / 256, 256, 0, stream>>>(U + U_POD, U + U_PDT, el_src, el_dst,
                                                  W + F_BFUSE, dec_w2, dec_b2, (float*)d_out);
}